// Round 7
// baseline (751.917 us; speedup 1.0000x reference)
//
#include <hip/hip_runtime.h>
#include <math.h>

#define T_TOKENS 16384
#define H_DIM 1024
#define F_DIM 2048
#define E_NUM 8
#define TPR 72                      // 256-row tiles per rank (16384/256 + 8 pad)
#define TOT_T (2 * TPR)             // 144
#define MAX_PAIRS (TOT_T * 256)     // 36864

typedef __attribute__((ext_vector_type(8))) short bf16x8;
typedef __attribute__((ext_vector_type(4))) float f32x4;
typedef __attribute__((ext_vector_type(4))) unsigned short us4;

struct TopK { int e0, e1; float w0, w1; };

__device__ __forceinline__ unsigned short f2bf(float f) {
  unsigned int u = __float_as_uint(f);
  u = (u + 0x7fffu + ((u >> 16) & 1u)) >> 16;
  return (unsigned short)u;
}

__device__ __forceinline__ void gload_lds16(const void* g, void* l) {
  __builtin_amdgcn_global_load_lds(
      (const __attribute__((address_space(1))) void*)g,
      (__attribute__((address_space(3))) void*)l, 16, 0, 0);
}

// ---------------- cast + transpose weights: in [E][R][C] f32 -> out [E][C][R] bf16
__global__ __launch_bounds__(256) void transpose_cast(
    const float* __restrict__ in, unsigned short* __restrict__ out, int R, int C) {
  __shared__ float tile[64][65];
  int e = blockIdx.z;
  int r0 = blockIdx.y * 64, c0 = blockIdx.x * 64;
  int tid = threadIdx.x;
  const float* src = in + ((size_t)e * R + r0) * C + c0;
#pragma unroll
  for (int p = 0; p < 4; p++) {
    int id = p * 256 + tid;
    int row = id >> 4, c4 = (id & 15) * 4;
    float4 v = *(const float4*)&src[(size_t)row * C + c4];
    tile[row][c4 + 0] = v.x; tile[row][c4 + 1] = v.y;
    tile[row][c4 + 2] = v.z; tile[row][c4 + 3] = v.w;
  }
  __syncthreads();
  unsigned short* dst = out + ((size_t)e * C + c0) * R + r0;
#pragma unroll
  for (int p = 0; p < 4; p++) {
    int id = p * 256 + tid;
    int c = id >> 4, r4 = (id & 15) * 4;
    us4 pk;
#pragma unroll
    for (int j = 0; j < 4; j++) pk[j] = f2bf(tile[r4 + j][c]);
    *(us4*)&dst[(size_t)c * R + r4] = pk;
  }
}

// ---------------- router: logits (f32), softmax, top-2, losses, counts, x->bf16
__global__ __launch_bounds__(256) void router_kernel(
    const float* __restrict__ x, const float* __restrict__ Wg,
    unsigned short* __restrict__ xb, TopK* __restrict__ topk,
    int* __restrict__ counts, float* __restrict__ scal) {
  __shared__ float wg[E_NUM][H_DIM];
  __shared__ int cnt[16];
  __shared__ float sred[4][5];
  int tid = threadIdx.x;
  if (tid < 16) cnt[tid] = 0;
  for (int i = tid; i < E_NUM * H_DIM; i += 256) wg[i & 7][i >> 3] = Wg[i];
  __syncthreads();
  int lane = tid & 63, wid = tid >> 6;
  float zacc = 0.f, c0 = 0.f, c1 = 0.f, s0 = 0.f, s1 = 0.f;
  int wgid = blockIdx.x * 4 + wid;
#pragma unroll
  for (int it = 0; it < 4; ++it) {
    int t = wgid + it * 4096;
    const float4* xr = (const float4*)(x + (size_t)t * H_DIM);
    us4* xbr = (us4*)(xb + (size_t)t * H_DIM);
    float l[E_NUM];
#pragma unroll
    for (int e = 0; e < E_NUM; e++) l[e] = 0.f;
#pragma unroll
    for (int i = 0; i < 4; i++) {
      int j = i * 64 + lane;
      float4 v = xr[j];
      us4 pk;
      pk[0] = f2bf(v.x); pk[1] = f2bf(v.y); pk[2] = f2bf(v.z); pk[3] = f2bf(v.w);
      xbr[j] = pk;
      int h = j * 4;
#pragma unroll
      for (int e = 0; e < E_NUM; e++) {
        const f32x4 wv = *(const f32x4*)&wg[e][h];
        l[e] = fmaf(v.x, wv[0], l[e]);
        l[e] = fmaf(v.y, wv[1], l[e]);
        l[e] = fmaf(v.z, wv[2], l[e]);
        l[e] = fmaf(v.w, wv[3], l[e]);
      }
    }
#pragma unroll
    for (int off = 32; off > 0; off >>= 1) {
#pragma unroll
      for (int e = 0; e < E_NUM; e++) l[e] += __shfl_xor(l[e], off, 64);
    }
    if (lane == 0) {
      float mx = l[0];
#pragma unroll
      for (int e = 1; e < E_NUM; e++) mx = fmaxf(mx, l[e]);
      float p[E_NUM]; float se = 0.f;
#pragma unroll
      for (int e = 0; e < E_NUM; e++) { p[e] = expf(l[e] - mx); se += p[e]; }
      float logz = logf(se) + mx;
      int e0 = 0; float b0 = p[0];
#pragma unroll
      for (int e = 1; e < E_NUM; e++) if (p[e] > b0) { b0 = p[e]; e0 = e; }
      int e1 = -1; float b1 = -1.f;
#pragma unroll
      for (int e = 0; e < E_NUM; e++) if (e != e0 && p[e] > b1) { b1 = p[e]; e1 = e; }
      float w0 = b0 / se, w1 = b1 / se;
      TopK tk; tk.e0 = e0; tk.e1 = e1; tk.w0 = w0; tk.w1 = w1;
      topk[t] = tk;
      atomicAdd(&cnt[e0], 1);
      atomicAdd(&cnt[8 + e1], 1);
      zacc += logz * logz;
      c0 += (e0 == 0 || e1 == 0) ? 1.f : 0.f;
      c1 += (e0 == 1 || e1 == 1) ? 1.f : 0.f;
      s0 += w0; s1 += w1;
    }
  }
  if (lane == 0) {
    sred[wid][0] = zacc; sred[wid][1] = c0; sred[wid][2] = c1;
    sred[wid][3] = s0;   sred[wid][4] = s1;
  }
  __syncthreads();
  if (tid == 0) {
    float a[5] = {0.f, 0.f, 0.f, 0.f, 0.f};
    for (int w2 = 0; w2 < 4; w2++)
      for (int k = 0; k < 5; k++) a[k] += sred[w2][k];
    for (int k = 0; k < 5; k++) atomicAdd(&scal[k], a[k]);
  }
  if (tid < 16 && cnt[tid]) atomicAdd(&counts[tid], cnt[tid]);
}

// ---------------- offsets padded to 256 rows per (rank, expert)
__global__ void scan_kernel(const int* __restrict__ counts, int* __restrict__ po,
                            int* __restrict__ tile_expert) {
  if (threadIdx.x == 0) {
    for (int r = 0; r < 2; r++) {
      int off = 0, ti = 0;
      for (int e = 0; e < E_NUM; e++) {
        po[r * 8 + e] = r * TPR * 256 + off;
        int nt = (counts[r * 8 + e] + 255) >> 8;
        for (int j = 0; j < nt; j++) tile_expert[r * TPR + ti++] = e;
        off += nt << 8;
      }
      while (ti < TPR) tile_expert[r * TPR + ti++] = -1;
    }
  }
}

__global__ __launch_bounds__(256) void assign_kernel(
    const TopK* __restrict__ topk, const int* __restrict__ po,
    int* __restrict__ cursors, int* __restrict__ pair_token,
    float* __restrict__ pair_w) {
  int t = blockIdx.x * 256 + threadIdx.x;
  if (t >= T_TOKENS) return;
  TopK tk = topk[t];
  int p0 = po[tk.e0] + atomicAdd(&cursors[tk.e0], 1);
  pair_token[p0] = t; pair_w[p0] = tk.w0;
  int p1 = po[8 + tk.e1] + atomicAdd(&cursors[8 + tk.e1], 1);
  pair_token[p1] = t; pair_w[p1] = tk.w1;
}

// ---------------- grouped GEMM, 256x256 tile, 8 waves, BK=64
// Register-double-buffered fragments, ONE barrier + one waitcnt per K-tile.
// LDS 128KB dynamic: 2 bufs x { A_k0 16K | A_k1 16K | B_k0 16K | B_k1 16K }
// MODE 0: hmid[p,:] = gelu(xb[tok(p),:] @ W1t[e]^T)           (K=1024, N=2048)
// MODE 1: out[tok(p),:] = w(p) * (hmid[p,:] @ W2t[e]^T) store (K=2048, N=1024)
// MODE 2: out[tok(p),:] += w(p) * (hmid[p,:] @ W2t[e]^T) RMW  (K=2048, N=1024)
template <int MODE, int K, int N, int NTILES>
__global__ __launch_bounds__(512) void moe_gemm8(
    const unsigned short* __restrict__ A, const unsigned short* __restrict__ Bt,
    const int* __restrict__ pair_token, const float* __restrict__ pair_w,
    const int* __restrict__ tile_expert, int tile_base,
    unsigned short* __restrict__ hmid, float* __restrict__ outp) {
  constexpr int NBN = N / 256;
  constexpr int NBLK = NBN * NTILES;           // % 8 == 0 by construction
  constexpr int NTk = K / 64;
  int l = blockIdx.x;
  int c = (l & 7) * (NBLK / 8) + (l >> 3);     // bijective XCD-chunked remap
  int mt = tile_base + (c % NTILES);           // m fast-varying: XCD shares B n-panel
  int nb = c / NTILES;
  int e = tile_expert[mt];
  if (e < 0) return;
  int m0 = mt << 8, n0 = nb << 8;

  extern __shared__ __align__(16) char smem_raw[];
  unsigned short* lds = (unsigned short*)smem_raw;   // 65536 elems = 128KB

  int tid = threadIdx.x, lane = tid & 63, wid = tid >> 6;
  int wm = wid >> 2, wn = wid & 3;             // 2 x 4 wave grid, wave tile 128x64
  int lo = lane & 15, hi = lane >> 4;
  int sw = (lo >> 1) & 3;
  int xk = (hi ^ sw) * 8;                      // swizzled chunk within 32-elem half-row

  // read bases (element offsets within a buffer)
  int aRB = (wm * 128 + lo) * 32 + xk;         // + mh*2048 + mf*512 ; +8192 for ks1
  int bRB = 16384 + (wn * 64 + lo) * 32 + xk;  // + nf*512 ; +8192 for ks1

  // ---- stage side: thread (wid, j=0/1) owns rows r0, r1; source chunk pre-swizzled
  int r0 = wid * 32 + (lane >> 2);
  int r1 = r0 + 16;
  int csrc = (lane & 3) ^ ((lane >> 3) & 3);   // == (lane&3) ^ ((r>>1)&3), same for r0/r1
  const unsigned short *aB0, *aB1, *bB0, *bB1;
  if (MODE == 0) {
    int t0 = pair_token[m0 + r0]; if (t0 < 0) t0 = 0;
    int t1 = pair_token[m0 + r1]; if (t1 < 0) t1 = 0;
    aB0 = A + (size_t)t0 * K + csrc * 8;
    aB1 = A + (size_t)t1 * K + csrc * 8;
  } else {
    aB0 = A + (size_t)(m0 + r0) * K + csrc * 8;
    aB1 = A + (size_t)(m0 + r1) * K + csrc * 8;
  }
  bB0 = Bt + ((size_t)e * N + n0 + r0) * K + csrc * 8;
  bB1 = Bt + ((size_t)e * N + n0 + r1) * K + csrc * 8;
  int dA = wid * 1024;                         // dest elem base (+ lane*8 implicit)

  // stage whole 64-K-tile s into buffer at byte-elem offset bo (8 gloads)
#define STAGE(s, bo) do { int ko = (s) * 64; \
    gload_lds16(aB0 + ko,      lds + (bo) + dA); \
    gload_lds16(aB1 + ko,      lds + (bo) + dA + 512); \
    gload_lds16(aB0 + ko + 32, lds + (bo) + 8192 + dA); \
    gload_lds16(aB1 + ko + 32, lds + (bo) + 8192 + dA + 512); \
    gload_lds16(bB0 + ko,      lds + (bo) + 16384 + dA); \
    gload_lds16(bB1 + ko,      lds + (bo) + 16384 + dA + 512); \
    gload_lds16(bB0 + ko + 32, lds + (bo) + 24576 + dA); \
    gload_lds16(bB1 + ko + 32, lds + (bo) + 24576 + dA + 512); } while (0)
#define LDS_A(dst, bo, ks) do { _Pragma("unroll") \
    for (int mh = 0; mh < 2; mh++) _Pragma("unroll") \
    for (int mf = 0; mf < 4; mf++) \
      dst[mh * 4 + mf] = *(const bf16x8*)&lds[(bo) + (ks) * 8192 + aRB + mh * 2048 + mf * 512]; } while (0)
#define LDS_B(dst, bo, ks) do { _Pragma("unroll") \
    for (int nf = 0; nf < 4; nf++) \
      dst[nf] = *(const bf16x8*)&lds[(bo) + (ks) * 8192 + bRB + nf * 512]; } while (0)
#define MM32(aq, bq) do { __builtin_amdgcn_s_setprio(1); \
    _Pragma("unroll") for (int m = 0; m < 8; m++) \
    _Pragma("unroll") for (int n = 0; n < 4; n++) \
      acc[m][n] = __builtin_amdgcn_mfma_f32_16x16x32_bf16(bq[n], aq[m], acc[m][n], 0, 0, 0); \
    __builtin_amdgcn_s_setprio(0); } while (0)
#define SYNC() do { \
    asm volatile("s_waitcnt vmcnt(0) lgkmcnt(0)" ::: "memory"); \
    __builtin_amdgcn_sched_barrier(0); \
    asm volatile("s_barrier" ::: "memory"); \
    __builtin_amdgcn_sched_barrier(0); } while (0)

  f32x4 acc[8][4];
#pragma unroll
  for (int i = 0; i < 8; i++)
#pragma unroll
    for (int j = 0; j < 4; j++) acc[i][j] = (f32x4){0.f, 0.f, 0.f, 0.f};

  bf16x8 afrA[8], bfrA[4], afrB[8], bfrB[4];

  // prologue: stage tile0->buf0, tile1->buf1; wait tile0 (8 outstanding = tile1)
  STAGE(0, 0);
  STAGE(1, 32768);
  asm volatile("s_waitcnt vmcnt(8)" ::: "memory");
  __builtin_amdgcn_sched_barrier(0);
  asm volatile("s_barrier" ::: "memory");
  __builtin_amdgcn_sched_barrier(0);
  LDS_A(afrA, 0, 0);
  LDS_B(bfrA, 0, 0);

  for (int t = 0; t < NTk; ++t) {
    int bo = (t & 1) << 15, bn = bo ^ 32768;
    // ds_read (t, ks1) -> regB while MFMA consumes regA (t, ks0)
    LDS_A(afrB, bo, 1);
    LDS_B(bfrB, bo, 1);
    MM32(afrA, bfrA);
    // boundary: my reads of buf[t] done (lgkm), stage(t+1) landed (vm), all waves synced
    SYNC();
    if (t + 2 < NTk) STAGE(t + 2, bo);        // refill freed buffer, full-tile lead
    if (t + 1 < NTk) {                        // ds_read (t+1, ks0) -> regA
      LDS_A(afrA, bn, 0);
      LDS_B(bfrA, bn, 0);
    }
    MM32(afrB, bfrB);                         // (t, ks1); hides regA ds_read latency
  }
  // drain any outstanding global_load_lds before epilogue / endpgm
  asm volatile("s_waitcnt vmcnt(0)" ::: "memory");
  __builtin_amdgcn_sched_barrier(0);
#undef STAGE
#undef LDS_A
#undef LDS_B
#undef MM32
#undef SYNC

  if (MODE == 0) {
#pragma unroll
    for (int mh = 0; mh < 2; mh++)
#pragma unroll
      for (int mf = 0; mf < 4; mf++) {
        size_t p = m0 + wm * 128 + mh * 64 + mf * 16 + lo;
#pragma unroll
        for (int nf = 0; nf < 4; nf++) {
          int f = n0 + wn * 64 + nf * 16 + hi * 4;
          us4 pk;
#pragma unroll
          for (int r = 0; r < 4; r++) {
            float v = acc[mh * 4 + mf][nf][r];
            float u = fmaf(0.044715f * v * v, v, v);
            float s = 1.f / (1.f + __expf(-1.5957691216057308f * u));
            pk[r] = f2bf(v * s);
          }
          *(us4*)&hmid[p * (size_t)N + f] = pk;
        }
      }
  } else {
#pragma unroll
    for (int mh = 0; mh < 2; mh++)
#pragma unroll
      for (int mf = 0; mf < 4; mf++) {
        int p = m0 + wm * 128 + mh * 64 + mf * 16 + lo;
        int t = pair_token[p];
        if (t < 0) continue;
        float w = pair_w[p];
        float* orow = outp + (size_t)t * N;
#pragma unroll
        for (int nf = 0; nf < 4; nf++) {
          int f = n0 + wn * 64 + nf * 16 + hi * 4;
          f32x4 v;
#pragma unroll
          for (int r = 0; r < 4; r++) v[r] = w * acc[mh * 4 + mf][nf][r];
          if (MODE == 2) v += *(const f32x4*)&orow[f];  // non-atomic RMW: t unique per dispatch
          *(f32x4*)&orow[f] = v;
        }
      }
  }
}

__global__ void finalize_kernel(const float* __restrict__ scal,
                                float* __restrict__ outTail) {
  if (threadIdx.x == 0 && blockIdx.x == 0) {
    float invT = 1.f / (float)T_TOKENS;
    outTail[0] = scal[0] * invT;  // z_loss
    float tpe0 = scal[1] * invT, tpe1 = scal[2] * invT;
    float rp0 = scal[3] * invT, rp1 = scal[4] * invT;
    outTail[1] = (tpe0 * rp0 + tpe1 * rp1) * 0.5f * 4.f;  // aux (K=2 one_hot path)
  }
}

extern "C" void kernel_launch(void* const* d_in, const int* in_sizes, int n_in,
                              void* d_out, int out_size, void* d_ws, size_t ws_size,
                              hipStream_t stream) {
  const float* x  = (const float*)d_in[0];
  const float* Wg = (const float*)d_in[1];
  const float* W1 = (const float*)d_in[2];
  const float* W2 = (const float*)d_in[3];
  float* outp = (float*)d_out;

  char* w = (char*)d_ws;
  auto alloc = [&](size_t b) { char* p = w; w += (b + 511) & ~(size_t)511; return p; };
  // meta block: scal (8 f32) @ +0, counts (16 i32) @ +64, cursors (16 i32) @ +128
  char*  meta        = alloc(256);
  float* scal        = (float*)(meta + 0);
  int*   counts      = (int*)(meta + 64);
  int*   cursors     = (int*)(meta + 128);
  int*   po          = (int*)alloc(64);
  int*   tile_expert = (int*)alloc(TOT_T * 4);
  TopK*  topk        = (TopK*)alloc((size_t)T_TOKENS * sizeof(TopK));
  int*   pair_token  = (int*)alloc((size_t)MAX_PAIRS * 4);
  float* pair_w      = (float*)alloc((size_t)MAX_PAIRS * 4);
  // staged buffers padded +512B (staging tail prefetch may touch past end)
  unsigned short* xb   = (unsigned short*)alloc((size_t)T_TOKENS * H_DIM * 2 + 512);
  unsigned short* w1t  = (unsigned short*)alloc((size_t)E_NUM * F_DIM * H_DIM * 2 + 512);
  unsigned short* hmid = (unsigned short*)alloc((size_t)MAX_PAIRS * F_DIM * 2 + 512);
  // w2t ALIASES xb (xb dead after GEMM1; W2 transpose launched after GEMM1)
  unsigned short* w2t  = xb;

  // allow 128KB dynamic LDS for the GEMM kernels (host-side attr, capture-safe)
  hipFuncSetAttribute((const void*)&moe_gemm8<0, H_DIM, F_DIM, TOT_T>,
                      hipFuncAttributeMaxDynamicSharedMemorySize, 131072);
  hipFuncSetAttribute((const void*)&moe_gemm8<1, F_DIM, H_DIM, TPR>,
                      hipFuncAttributeMaxDynamicSharedMemorySize, 131072);
  hipFuncSetAttribute((const void*)&moe_gemm8<2, F_DIM, H_DIM, TPR>,
                      hipFuncAttributeMaxDynamicSharedMemorySize, 131072);

  hipMemsetAsync(meta, 0, 256, stream);
  hipMemsetAsync(pair_token, 0xFF, (size_t)MAX_PAIRS * 4, stream);  // -1

  dim3 b256(256), b512(512);
  // W1 [E][H][F] -> w1t [E][F][H]
  transpose_cast<<<dim3(F_DIM / 64, H_DIM / 64, E_NUM), b256, 0, stream>>>(W1, w1t, H_DIM, F_DIM);
  router_kernel<<<1024, b256, 0, stream>>>(x, Wg, xb, topk, counts, scal);
  scan_kernel<<<1, 64, 0, stream>>>(counts, po, tile_expert);
  assign_kernel<<<T_TOKENS / 256, b256, 0, stream>>>(topk, po, cursors, pair_token, pair_w);
  // GEMM1: hmid = gelu(gather(xb) @ W1t^T), both rank regions, one dispatch
  moe_gemm8<0, H_DIM, F_DIM, TOT_T><<<dim3((F_DIM / 256) * TOT_T), b512, 131072, stream>>>(
      xb, w1t, pair_token, pair_w, tile_expert, 0, hmid, nullptr);
  // W2 [E][F][H] -> w2t [E][H][F]  (into xb's space — xb dead now)
  transpose_cast<<<dim3(H_DIM / 64, F_DIM / 64, E_NUM), b256, 0, stream>>>(W2, w2t, F_DIM, H_DIM);
  // GEMM2 rank-0: plain store (every token exactly once)
  moe_gemm8<1, F_DIM, H_DIM, TPR><<<dim3((H_DIM / 256) * TPR), b512, 131072, stream>>>(
      hmid, w2t, pair_token, pair_w, tile_expert, 0, nullptr, outp);
  // GEMM2 rank-1: non-atomic RMW add (every token exactly once)
  moe_gemm8<2, F_DIM, H_DIM, TPR><<<dim3((H_DIM / 256) * TPR), b512, 131072, stream>>>(
      hmid, w2t, pair_token, pair_w, tile_expert, TPR, nullptr, outp);
  finalize_kernel<<<1, 64, 0, stream>>>(scal, outp + (size_t)T_TOKENS * H_DIM);
}

// Round 8
// 729.058 us; speedup vs baseline: 1.0314x; 1.0314x over previous
//
#include <hip/hip_runtime.h>
#include <math.h>

#define T_TOKENS 16384
#define H_DIM 1024
#define F_DIM 2048
#define E_NUM 8
#define TPR 72                      // 256-row tiles per rank (16384/256 + 8 pad)
#define TOT_T (2 * TPR)             // 144
#define MAX_PAIRS (TOT_T * 256)     // 36864

typedef __attribute__((ext_vector_type(8))) short bf16x8;
typedef __attribute__((ext_vector_type(4))) float f32x4;
typedef __attribute__((ext_vector_type(4))) unsigned short us4;

struct TopK { int e0, e1; float w0, w1; };

__device__ __forceinline__ unsigned short f2bf(float f) {
  unsigned int u = __float_as_uint(f);
  u = (u + 0x7fffu + ((u >> 16) & 1u)) >> 16;
  return (unsigned short)u;
}

__device__ __forceinline__ void gload_lds16(const void* g, void* l) {
  __builtin_amdgcn_global_load_lds(
      (const __attribute__((address_space(1))) void*)g,
      (__attribute__((address_space(3))) void*)l, 16, 0, 0);
}

// ---------------- cast + transpose weights: in [E][R][C] f32 -> out [E][C][R] bf16
__global__ __launch_bounds__(256) void transpose_cast(
    const float* __restrict__ in, unsigned short* __restrict__ out, int R, int C) {
  __shared__ float tile[64][65];
  int e = blockIdx.z;
  int r0 = blockIdx.y * 64, c0 = blockIdx.x * 64;
  int tid = threadIdx.x;
  const float* src = in + ((size_t)e * R + r0) * C + c0;
#pragma unroll
  for (int p = 0; p < 4; p++) {
    int id = p * 256 + tid;
    int row = id >> 4, c4 = (id & 15) * 4;
    float4 v = *(const float4*)&src[(size_t)row * C + c4];
    tile[row][c4 + 0] = v.x; tile[row][c4 + 1] = v.y;
    tile[row][c4 + 2] = v.z; tile[row][c4 + 3] = v.w;
  }
  __syncthreads();
  unsigned short* dst = out + ((size_t)e * C + c0) * R + r0;
#pragma unroll
  for (int p = 0; p < 4; p++) {
    int id = p * 256 + tid;
    int c = id >> 4, r4 = (id & 15) * 4;
    us4 pk;
#pragma unroll
    for (int j = 0; j < 4; j++) pk[j] = f2bf(tile[r4 + j][c]);
    *(us4*)&dst[(size_t)c * R + r4] = pk;
  }
}

// ---------------- router: logits (f32), softmax, top-2, losses, counts, x->bf16
__global__ __launch_bounds__(256) void router_kernel(
    const float* __restrict__ x, const float* __restrict__ Wg,
    unsigned short* __restrict__ xb, TopK* __restrict__ topk,
    int* __restrict__ counts, float* __restrict__ scal) {
  __shared__ float wg[E_NUM][H_DIM];
  __shared__ int cnt[16];
  __shared__ float sred[4][5];
  int tid = threadIdx.x;
  if (tid < 16) cnt[tid] = 0;
  for (int i = tid; i < E_NUM * H_DIM; i += 256) wg[i & 7][i >> 3] = Wg[i];
  __syncthreads();
  int lane = tid & 63, wid = tid >> 6;
  float zacc = 0.f, c0 = 0.f, c1 = 0.f, s0 = 0.f, s1 = 0.f;
  int wgid = blockIdx.x * 4 + wid;
#pragma unroll
  for (int it = 0; it < 4; ++it) {
    int t = wgid + it * 4096;
    const float4* xr = (const float4*)(x + (size_t)t * H_DIM);
    us4* xbr = (us4*)(xb + (size_t)t * H_DIM);
    float l[E_NUM];
#pragma unroll
    for (int e = 0; e < E_NUM; e++) l[e] = 0.f;
#pragma unroll
    for (int i = 0; i < 4; i++) {
      int j = i * 64 + lane;
      float4 v = xr[j];
      us4 pk;
      pk[0] = f2bf(v.x); pk[1] = f2bf(v.y); pk[2] = f2bf(v.z); pk[3] = f2bf(v.w);
      xbr[j] = pk;
      int h = j * 4;
#pragma unroll
      for (int e = 0; e < E_NUM; e++) {
        const f32x4 wv = *(const f32x4*)&wg[e][h];
        l[e] = fmaf(v.x, wv[0], l[e]);
        l[e] = fmaf(v.y, wv[1], l[e]);
        l[e] = fmaf(v.z, wv[2], l[e]);
        l[e] = fmaf(v.w, wv[3], l[e]);
      }
    }
#pragma unroll
    for (int off = 32; off > 0; off >>= 1) {
#pragma unroll
      for (int e = 0; e < E_NUM; e++) l[e] += __shfl_xor(l[e], off, 64);
    }
    if (lane == 0) {
      float mx = l[0];
#pragma unroll
      for (int e = 1; e < E_NUM; e++) mx = fmaxf(mx, l[e]);
      float p[E_NUM]; float se = 0.f;
#pragma unroll
      for (int e = 0; e < E_NUM; e++) { p[e] = expf(l[e] - mx); se += p[e]; }
      float logz = logf(se) + mx;
      int e0 = 0; float b0 = p[0];
#pragma unroll
      for (int e = 1; e < E_NUM; e++) if (p[e] > b0) { b0 = p[e]; e0 = e; }
      int e1 = -1; float b1 = -1.f;
#pragma unroll
      for (int e = 0; e < E_NUM; e++) if (e != e0 && p[e] > b1) { b1 = p[e]; e1 = e; }
      float w0 = b0 / se, w1 = b1 / se;
      TopK tk; tk.e0 = e0; tk.e1 = e1; tk.w0 = w0; tk.w1 = w1;
      topk[t] = tk;
      atomicAdd(&cnt[e0], 1);
      atomicAdd(&cnt[8 + e1], 1);
      zacc += logz * logz;
      c0 += (e0 == 0 || e1 == 0) ? 1.f : 0.f;
      c1 += (e0 == 1 || e1 == 1) ? 1.f : 0.f;
      s0 += w0; s1 += w1;
    }
  }
  if (lane == 0) {
    sred[wid][0] = zacc; sred[wid][1] = c0; sred[wid][2] = c1;
    sred[wid][3] = s0;   sred[wid][4] = s1;
  }
  __syncthreads();
  if (tid == 0) {
    float a[5] = {0.f, 0.f, 0.f, 0.f, 0.f};
    for (int w2 = 0; w2 < 4; w2++)
      for (int k = 0; k < 5; k++) a[k] += sred[w2][k];
    for (int k = 0; k < 5; k++) atomicAdd(&scal[k], a[k]);
  }
  if (tid < 16 && cnt[tid]) atomicAdd(&counts[tid], cnt[tid]);
}

// ---------------- offsets padded to 256 rows per (rank, expert) — parallel version
__global__ __launch_bounds__(256) void scan_kernel(
    const int* __restrict__ counts, int* __restrict__ po,
    int* __restrict__ tile_expert) {
  __shared__ int nt[16], start[16];
  int tid = threadIdx.x;
  if (tid < 16) {
    int r = tid >> 3, e = tid & 7;
    int s = 0;
    for (int j = 0; j < e; j++) s += (counts[(r << 3) + j] + 255) >> 8;
    nt[tid] = (counts[tid] + 255) >> 8;
    start[tid] = s;
    po[tid] = r * TPR * 256 + (s << 8);
  }
  __syncthreads();
  for (int ti = tid; ti < TOT_T; ti += 256) {
    int r = ti / TPR, local = ti % TPR;
    int ex = -1;
#pragma unroll
    for (int e = 0; e < E_NUM; e++) {
      int k = (r << 3) + e;
      if (local >= start[k] && local < start[k] + nt[k]) ex = e;
    }
    tile_expert[ti] = ex;
  }
}

__global__ __launch_bounds__(256) void assign_kernel(
    const TopK* __restrict__ topk, const int* __restrict__ po,
    int* __restrict__ cursors, int* __restrict__ pair_token,
    float* __restrict__ pair_w) {
  int t = blockIdx.x * 256 + threadIdx.x;
  if (t >= T_TOKENS) return;
  TopK tk = topk[t];
  int p0 = po[tk.e0] + atomicAdd(&cursors[tk.e0], 1);
  pair_token[p0] = t; pair_w[p0] = tk.w0;
  int p1 = po[8 + tk.e1] + atomicAdd(&cursors[8 + tk.e1], 1);
  pair_token[p1] = t; pair_w[p1] = tk.w1;
}

// ---------------- grouped GEMM, 256x256 tile, 8 waves, BK=64
// Register-double-buffered fragments, ONE barrier + one waitcnt per K-tile.
// XCD mapping: each XCD owns NTILES/8 contiguous m-tiles, nb fast-varying ->
// concurrent blocks on an XCD share A panels (L2) and one expert's B panels.
// LDS 128KB dynamic: 2 bufs x { A_k0 16K | A_k1 16K | B_k0 16K | B_k1 16K }
// MODE 0: hmid[p,:] = gelu(xb[tok(p),:] @ W1t[e]^T)           (K=1024, N=2048)
// MODE 1: out[tok(p),:] = w(p) * (hmid[p,:] @ W2t[e]^T) store (K=2048, N=1024)
// MODE 2: out[tok(p),:] += w(p) * (hmid[p,:] @ W2t[e]^T) RMW  (K=2048, N=1024)
template <int MODE, int K, int N, int NTILES>
__global__ __launch_bounds__(512) void moe_gemm8(
    const unsigned short* __restrict__ A, const unsigned short* __restrict__ Bt,
    const int* __restrict__ pair_token, const float* __restrict__ pair_w,
    const int* __restrict__ tile_expert, int tile_base,
    unsigned short* __restrict__ hmid, float* __restrict__ outp) {
  constexpr int NBN = N / 256;
  constexpr int NTk = K / 64;
  constexpr int MTC = NTILES / 8;              // m-tiles per XCD
  int l = blockIdx.x;
  int xcd = l & 7, idx = l >> 3;               // assumes HW xcd = blockIdx % 8
  int mt = tile_base + xcd * MTC + idx / NBN;  // m chunked per XCD
  int nb = idx % NBN;                          // n fast-varying among concurrent
  int e = tile_expert[mt];
  if (e < 0) return;
  int m0 = mt << 8, n0 = nb << 8;

  extern __shared__ __align__(16) char smem_raw[];
  unsigned short* lds = (unsigned short*)smem_raw;   // 65536 elems = 128KB

  int tid = threadIdx.x, lane = tid & 63, wid = tid >> 6;
  int wm = wid >> 2, wn = wid & 3;             // 2 x 4 wave grid, wave tile 128x64
  int lo = lane & 15, hi = lane >> 4;
  int sw = (lo >> 1) & 3;
  int xk = (hi ^ sw) * 8;                      // swizzled chunk within 32-elem half-row

  // read bases (element offsets within a buffer)
  int aRB = (wm * 128 + lo) * 32 + xk;         // + mh*2048 + mf*512 ; +8192 for ks1
  int bRB = 16384 + (wn * 64 + lo) * 32 + xk;  // + nf*512 ; +8192 for ks1

  // ---- stage side: thread (wid, j=0/1) owns rows r0, r1; source chunk pre-swizzled
  int r0 = wid * 32 + (lane >> 2);
  int r1 = r0 + 16;
  int csrc = (lane & 3) ^ ((lane >> 3) & 3);   // == (lane&3) ^ ((r>>1)&3), same for r0/r1
  const unsigned short *aB0, *aB1, *bB0, *bB1;
  if (MODE == 0) {
    int t0 = pair_token[m0 + r0]; if (t0 < 0) t0 = 0;
    int t1 = pair_token[m0 + r1]; if (t1 < 0) t1 = 0;
    aB0 = A + (size_t)t0 * K + csrc * 8;
    aB1 = A + (size_t)t1 * K + csrc * 8;
  } else {
    aB0 = A + (size_t)(m0 + r0) * K + csrc * 8;
    aB1 = A + (size_t)(m0 + r1) * K + csrc * 8;
  }
  bB0 = Bt + ((size_t)e * N + n0 + r0) * K + csrc * 8;
  bB1 = Bt + ((size_t)e * N + n0 + r1) * K + csrc * 8;
  int dA = wid * 1024;                         // dest elem base (+ lane*8 implicit)

  // stage whole 64-K-tile s into buffer at elem offset bo (8 gloads)
#define STAGE(s, bo) do { int ko = (s) * 64; \
    gload_lds16(aB0 + ko,      lds + (bo) + dA); \
    gload_lds16(aB1 + ko,      lds + (bo) + dA + 512); \
    gload_lds16(aB0 + ko + 32, lds + (bo) + 8192 + dA); \
    gload_lds16(aB1 + ko + 32, lds + (bo) + 8192 + dA + 512); \
    gload_lds16(bB0 + ko,      lds + (bo) + 16384 + dA); \
    gload_lds16(bB1 + ko,      lds + (bo) + 16384 + dA + 512); \
    gload_lds16(bB0 + ko + 32, lds + (bo) + 24576 + dA); \
    gload_lds16(bB1 + ko + 32, lds + (bo) + 24576 + dA + 512); } while (0)
#define LDS_A(dst, bo, ks) do { _Pragma("unroll") \
    for (int mh = 0; mh < 2; mh++) _Pragma("unroll") \
    for (int mf = 0; mf < 4; mf++) \
      dst[mh * 4 + mf] = *(const bf16x8*)&lds[(bo) + (ks) * 8192 + aRB + mh * 2048 + mf * 512]; } while (0)
#define LDS_B(dst, bo, ks) do { _Pragma("unroll") \
    for (int nf = 0; nf < 4; nf++) \
      dst[nf] = *(const bf16x8*)&lds[(bo) + (ks) * 8192 + bRB + nf * 512]; } while (0)
#define MM32(aq, bq) do { __builtin_amdgcn_s_setprio(1); \
    _Pragma("unroll") for (int m = 0; m < 8; m++) \
    _Pragma("unroll") for (int n = 0; n < 4; n++) \
      acc[m][n] = __builtin_amdgcn_mfma_f32_16x16x32_bf16(bq[n], aq[m], acc[m][n], 0, 0, 0); \
    __builtin_amdgcn_s_setprio(0); } while (0)
#define SYNC() do { \
    asm volatile("s_waitcnt vmcnt(0) lgkmcnt(0)" ::: "memory"); \
    __builtin_amdgcn_sched_barrier(0); \
    asm volatile("s_barrier" ::: "memory"); \
    __builtin_amdgcn_sched_barrier(0); } while (0)

  f32x4 acc[8][4];
#pragma unroll
  for (int i = 0; i < 8; i++)
#pragma unroll
    for (int j = 0; j < 4; j++) acc[i][j] = (f32x4){0.f, 0.f, 0.f, 0.f};

  bf16x8 afrA[8], bfrA[4], afrB[8], bfrB[4];

  // prologue: stage tile0->buf0, tile1->buf1; wait tile0 (8 outstanding = tile1)
  STAGE(0, 0);
  STAGE(1, 32768);
  asm volatile("s_waitcnt vmcnt(8)" ::: "memory");
  __builtin_amdgcn_sched_barrier(0);
  asm volatile("s_barrier" ::: "memory");
  __builtin_amdgcn_sched_barrier(0);
  LDS_A(afrA, 0, 0);
  LDS_B(bfrA, 0, 0);

  for (int t = 0; t < NTk; ++t) {
    int bo = (t & 1) << 15, bn = bo ^ 32768;
    // ds_read (t, ks1) -> regB while MFMA consumes regA (t, ks0)
    LDS_A(afrB, bo, 1);
    LDS_B(bfrB, bo, 1);
    MM32(afrA, bfrA);
    // boundary: my reads of buf[t] done (lgkm), stage(t+1) landed (vm), all waves synced
    SYNC();
    if (t + 2 < NTk) STAGE(t + 2, bo);        // refill freed buffer, full-tile lead
    if (t + 1 < NTk) {                        // ds_read (t+1, ks0) -> regA
      LDS_A(afrA, bn, 0);
      LDS_B(bfrA, bn, 0);
    }
    MM32(afrB, bfrB);                         // (t, ks1); hides regA ds_read latency
  }
  // drain any outstanding global_load_lds before epilogue / endpgm
  asm volatile("s_waitcnt vmcnt(0)" ::: "memory");
  __builtin_amdgcn_sched_barrier(0);
#undef STAGE
#undef LDS_A
#undef LDS_B
#undef MM32
#undef SYNC

  if (MODE == 0) {
#pragma unroll
    for (int mh = 0; mh < 2; mh++)
#pragma unroll
      for (int mf = 0; mf < 4; mf++) {
        size_t p = m0 + wm * 128 + mh * 64 + mf * 16 + lo;
#pragma unroll
        for (int nf = 0; nf < 4; nf++) {
          int f = n0 + wn * 64 + nf * 16 + hi * 4;
          us4 pk;
#pragma unroll
          for (int r = 0; r < 4; r++) {
            float v = acc[mh * 4 + mf][nf][r];
            float u = fmaf(0.044715f * v * v, v, v);
            float s = 1.f / (1.f + __expf(-1.5957691216057308f * u));
            pk[r] = f2bf(v * s);
          }
          *(us4*)&hmid[p * (size_t)N + f] = pk;
        }
      }
  } else {
#pragma unroll
    for (int mh = 0; mh < 2; mh++)
#pragma unroll
      for (int mf = 0; mf < 4; mf++) {
        int p = m0 + wm * 128 + mh * 64 + mf * 16 + lo;
        int t = pair_token[p];
        if (t < 0) continue;
        float w = pair_w[p];
        float* orow = outp + (size_t)t * N;
#pragma unroll
        for (int nf = 0; nf < 4; nf++) {
          int f = n0 + wn * 64 + nf * 16 + hi * 4;
          f32x4 v;
#pragma unroll
          for (int r = 0; r < 4; r++) v[r] = w * acc[mh * 4 + mf][nf][r];
          if (MODE == 2) v += *(const f32x4*)&orow[f];  // non-atomic RMW: t unique per dispatch
          *(f32x4*)&orow[f] = v;
        }
      }
  }
}

__global__ void finalize_kernel(const float* __restrict__ scal,
                                float* __restrict__ outTail) {
  if (threadIdx.x == 0 && blockIdx.x == 0) {
    float invT = 1.f / (float)T_TOKENS;
    outTail[0] = scal[0] * invT;  // z_loss
    float tpe0 = scal[1] * invT, tpe1 = scal[2] * invT;
    float rp0 = scal[3] * invT, rp1 = scal[4] * invT;
    outTail[1] = (tpe0 * rp0 + tpe1 * rp1) * 0.5f * 4.f;  // aux (K=2 one_hot path)
  }
}

extern "C" void kernel_launch(void* const* d_in, const int* in_sizes, int n_in,
                              void* d_out, int out_size, void* d_ws, size_t ws_size,
                              hipStream_t stream) {
  const float* x  = (const float*)d_in[0];
  const float* Wg = (const float*)d_in[1];
  const float* W1 = (const float*)d_in[2];
  const float* W2 = (const float*)d_in[3];
  float* outp = (float*)d_out;

  char* w = (char*)d_ws;
  auto alloc = [&](size_t b) { char* p = w; w += (b + 511) & ~(size_t)511; return p; };
  // meta block: scal (8 f32) @ +0, counts (16 i32) @ +64, cursors (16 i32) @ +128
  char*  meta        = alloc(256);
  float* scal        = (float*)(meta + 0);
  int*   counts      = (int*)(meta + 64);
  int*   cursors     = (int*)(meta + 128);
  int*   po          = (int*)alloc(64);
  int*   tile_expert = (int*)alloc(TOT_T * 4);
  TopK*  topk        = (TopK*)alloc((size_t)T_TOKENS * sizeof(TopK));
  int*   pair_token  = (int*)alloc((size_t)MAX_PAIRS * 4);
  float* pair_w      = (float*)alloc((size_t)MAX_PAIRS * 4);
  // staged buffers padded +512B (staging tail prefetch may touch past end)
  unsigned short* xb   = (unsigned short*)alloc((size_t)T_TOKENS * H_DIM * 2 + 512);
  unsigned short* w1t  = (unsigned short*)alloc((size_t)E_NUM * F_DIM * H_DIM * 2 + 512);
  unsigned short* hmid = (unsigned short*)alloc((size_t)MAX_PAIRS * F_DIM * 2 + 512);
  // w2t ALIASES xb (xb dead after GEMM1; W2 transpose launched after GEMM1)
  unsigned short* w2t  = xb;

  // allow 128KB dynamic LDS for the GEMM kernels (host-side attr, capture-safe)
  hipFuncSetAttribute((const void*)&moe_gemm8<0, H_DIM, F_DIM, TOT_T>,
                      hipFuncAttributeMaxDynamicSharedMemorySize, 131072);
  hipFuncSetAttribute((const void*)&moe_gemm8<1, F_DIM, H_DIM, TPR>,
                      hipFuncAttributeMaxDynamicSharedMemorySize, 131072);
  hipFuncSetAttribute((const void*)&moe_gemm8<2, F_DIM, H_DIM, TPR>,
                      hipFuncAttributeMaxDynamicSharedMemorySize, 131072);

  hipMemsetAsync(meta, 0, 256, stream);
  hipMemsetAsync(pair_token, 0xFF, (size_t)MAX_PAIRS * 4, stream);  // -1

  dim3 b256(256), b512(512);
  // W1 [E][H][F] -> w1t [E][F][H]
  transpose_cast<<<dim3(F_DIM / 64, H_DIM / 64, E_NUM), b256, 0, stream>>>(W1, w1t, H_DIM, F_DIM);
  router_kernel<<<1024, b256, 0, stream>>>(x, Wg, xb, topk, counts, scal);
  scan_kernel<<<1, b256, 0, stream>>>(counts, po, tile_expert);
  assign_kernel<<<T_TOKENS / 256, b256, 0, stream>>>(topk, po, cursors, pair_token, pair_w);
  // GEMM1: hmid = gelu(gather(xb) @ W1t^T), both rank regions, one dispatch
  moe_gemm8<0, H_DIM, F_DIM, TOT_T><<<dim3((F_DIM / 256) * TOT_T), b512, 131072, stream>>>(
      xb, w1t, pair_token, pair_w, tile_expert, 0, hmid, nullptr);
  // W2 [E][F][H] -> w2t [E][H][F]  (into xb's space — xb dead now)
  transpose_cast<<<dim3(H_DIM / 64, F_DIM / 64, E_NUM), b256, 0, stream>>>(W2, w2t, F_DIM, H_DIM);
  // GEMM2 rank-0: plain store (every token exactly once)
  moe_gemm8<1, F_DIM, H_DIM, TPR><<<dim3((H_DIM / 256) * TPR), b512, 131072, stream>>>(
      hmid, w2t, pair_token, pair_w, tile_expert, 0, nullptr, outp);
  // GEMM2 rank-1: non-atomic RMW add (every token exactly once)
  moe_gemm8<2, F_DIM, H_DIM, TPR><<<dim3((H_DIM / 256) * TPR), b512, 131072, stream>>>(
      hmid, w2t, pair_token, pair_w, tile_expert, TPR, nullptr, outp);
  finalize_kernel<<<1, 64, 0, stream>>>(scal, outp + (size_t)T_TOKENS * H_DIM);
}

// Round 9
// 661.770 us; speedup vs baseline: 1.1362x; 1.1017x over previous
//
#include <hip/hip_runtime.h>
#include <math.h>

#define T_TOKENS 16384
#define H_DIM 1024
#define F_DIM 2048
#define E_NUM 8
#define TPR 72                      // 256-row tiles per rank (16384/256 + 8 pad)
#define TOT_T (2 * TPR)             // 144
#define MAX_PAIRS (TOT_T * 256)     // 36864

typedef __attribute__((ext_vector_type(8))) short bf16x8;
typedef __attribute__((ext_vector_type(4))) float f32x4;
typedef __attribute__((ext_vector_type(4))) unsigned short us4;

struct TopK { int e0, e1; float w0, w1; };

__device__ __forceinline__ unsigned short f2bf(float f) {
  unsigned int u = __float_as_uint(f);
  u = (u + 0x7fffu + ((u >> 16) & 1u)) >> 16;
  return (unsigned short)u;
}

__device__ __forceinline__ float bf2f(unsigned short u) {
  return __uint_as_float(((unsigned int)u) << 16);
}

__device__ __forceinline__ void gload_lds16(const void* g, void* l) {
  __builtin_amdgcn_global_load_lds(
      (const __attribute__((address_space(1))) void*)g,
      (__attribute__((address_space(3))) void*)l, 16, 0, 0);
}

// ---------------- cast + transpose weights: in [E][R][C] f32 -> out [E][C][R] bf16
__global__ __launch_bounds__(256) void transpose_cast(
    const float* __restrict__ in, unsigned short* __restrict__ out, int R, int C) {
  __shared__ float tile[64][65];
  int e = blockIdx.z;
  int r0 = blockIdx.y * 64, c0 = blockIdx.x * 64;
  int tid = threadIdx.x;
  const float* src = in + ((size_t)e * R + r0) * C + c0;
#pragma unroll
  for (int p = 0; p < 4; p++) {
    int id = p * 256 + tid;
    int row = id >> 4, c4 = (id & 15) * 4;
    float4 v = *(const float4*)&src[(size_t)row * C + c4];
    tile[row][c4 + 0] = v.x; tile[row][c4 + 1] = v.y;
    tile[row][c4 + 2] = v.z; tile[row][c4 + 3] = v.w;
  }
  __syncthreads();
  unsigned short* dst = out + ((size_t)e * C + c0) * R + r0;
#pragma unroll
  for (int p = 0; p < 4; p++) {
    int id = p * 256 + tid;
    int c = id >> 4, r4 = (id & 15) * 4;
    us4 pk;
#pragma unroll
    for (int j = 0; j < 4; j++) pk[j] = f2bf(tile[r4 + j][c]);
    *(us4*)&dst[(size_t)c * R + r4] = pk;
  }
}

// ---------------- router: logits (f32), softmax, top-2, losses, counts, x->bf16
__global__ __launch_bounds__(256) void router_kernel(
    const float* __restrict__ x, const float* __restrict__ Wg,
    unsigned short* __restrict__ xb, TopK* __restrict__ topk,
    int* __restrict__ counts, float* __restrict__ scal) {
  __shared__ float wg[E_NUM][H_DIM];
  __shared__ int cnt[16];
  __shared__ float sred[4][5];
  int tid = threadIdx.x;
  if (tid < 16) cnt[tid] = 0;
  for (int i = tid; i < E_NUM * H_DIM; i += 256) wg[i & 7][i >> 3] = Wg[i];
  __syncthreads();
  int lane = tid & 63, wid = tid >> 6;
  float zacc = 0.f, c0 = 0.f, c1 = 0.f, s0 = 0.f, s1 = 0.f;
  int wgid = blockIdx.x * 4 + wid;
#pragma unroll
  for (int it = 0; it < 4; ++it) {
    int t = wgid + it * 4096;
    const float4* xr = (const float4*)(x + (size_t)t * H_DIM);
    us4* xbr = (us4*)(xb + (size_t)t * H_DIM);
    float l[E_NUM];
#pragma unroll
    for (int e = 0; e < E_NUM; e++) l[e] = 0.f;
#pragma unroll
    for (int i = 0; i < 4; i++) {
      int j = i * 64 + lane;
      float4 v = xr[j];
      us4 pk;
      pk[0] = f2bf(v.x); pk[1] = f2bf(v.y); pk[2] = f2bf(v.z); pk[3] = f2bf(v.w);
      xbr[j] = pk;
      int h = j * 4;
#pragma unroll
      for (int e = 0; e < E_NUM; e++) {
        const f32x4 wv = *(const f32x4*)&wg[e][h];
        l[e] = fmaf(v.x, wv[0], l[e]);
        l[e] = fmaf(v.y, wv[1], l[e]);
        l[e] = fmaf(v.z, wv[2], l[e]);
        l[e] = fmaf(v.w, wv[3], l[e]);
      }
    }
#pragma unroll
    for (int off = 32; off > 0; off >>= 1) {
#pragma unroll
      for (int e = 0; e < E_NUM; e++) l[e] += __shfl_xor(l[e], off, 64);
    }
    if (lane == 0) {
      float mx = l[0];
#pragma unroll
      for (int e = 1; e < E_NUM; e++) mx = fmaxf(mx, l[e]);
      float p[E_NUM]; float se = 0.f;
#pragma unroll
      for (int e = 0; e < E_NUM; e++) { p[e] = expf(l[e] - mx); se += p[e]; }
      float logz = logf(se) + mx;
      int e0 = 0; float b0 = p[0];
#pragma unroll
      for (int e = 1; e < E_NUM; e++) if (p[e] > b0) { b0 = p[e]; e0 = e; }
      int e1 = -1; float b1 = -1.f;
#pragma unroll
      for (int e = 0; e < E_NUM; e++) if (e != e0 && p[e] > b1) { b1 = p[e]; e1 = e; }
      float w0 = b0 / se, w1 = b1 / se;
      TopK tk; tk.e0 = e0; tk.e1 = e1; tk.w0 = w0; tk.w1 = w1;
      topk[t] = tk;
      atomicAdd(&cnt[e0], 1);
      atomicAdd(&cnt[8 + e1], 1);
      zacc += logz * logz;
      c0 += (e0 == 0 || e1 == 0) ? 1.f : 0.f;
      c1 += (e0 == 1 || e1 == 1) ? 1.f : 0.f;
      s0 += w0; s1 += w1;
    }
  }
  if (lane == 0) {
    sred[wid][0] = zacc; sred[wid][1] = c0; sred[wid][2] = c1;
    sred[wid][3] = s0;   sred[wid][4] = s1;
  }
  __syncthreads();
  if (tid == 0) {
    float a[5] = {0.f, 0.f, 0.f, 0.f, 0.f};
    for (int w2 = 0; w2 < 4; w2++)
      for (int k = 0; k < 5; k++) a[k] += sred[w2][k];
    for (int k = 0; k < 5; k++) atomicAdd(&scal[k], a[k]);
  }
  if (tid < 16 && cnt[tid]) atomicAdd(&counts[tid], cnt[tid]);
}

// ---------------- offsets padded to 256 rows per (rank, expert) — parallel version
__global__ __launch_bounds__(256) void scan_kernel(
    const int* __restrict__ counts, int* __restrict__ po,
    int* __restrict__ tile_expert) {
  __shared__ int nt[16], start[16];
  int tid = threadIdx.x;
  if (tid < 16) {
    int r = tid >> 3, e = tid & 7;
    int s = 0;
    for (int j = 0; j < e; j++) s += (counts[(r << 3) + j] + 255) >> 8;
    nt[tid] = (counts[tid] + 255) >> 8;
    start[tid] = s;
    po[tid] = r * TPR * 256 + (s << 8);
  }
  __syncthreads();
  for (int ti = tid; ti < TOT_T; ti += 256) {
    int r = ti / TPR, local = ti % TPR;
    int ex = -1;
#pragma unroll
    for (int e = 0; e < E_NUM; e++) {
      int k = (r << 3) + e;
      if (local >= start[k] && local < start[k] + nt[k]) ex = e;
    }
    tile_expert[ti] = ex;
  }
}

__global__ __launch_bounds__(256) void assign_kernel(
    const TopK* __restrict__ topk, const int* __restrict__ po,
    int* __restrict__ cursors, int* __restrict__ pair_token,
    float* __restrict__ pair_w, int* __restrict__ inv0, int* __restrict__ inv1) {
  int t = blockIdx.x * 256 + threadIdx.x;
  if (t >= T_TOKENS) return;
  TopK tk = topk[t];
  int p0 = po[tk.e0] + atomicAdd(&cursors[tk.e0], 1);
  pair_token[p0] = t; pair_w[p0] = tk.w0; inv0[t] = p0;
  int p1 = po[8 + tk.e1] + atomicAdd(&cursors[8 + tk.e1], 1);
  pair_token[p1] = t; pair_w[p1] = tk.w1; inv1[t] = p1;
}

// ---------------- grouped GEMM, 256x256 tile, 8 waves, BK=64
// Register-double-buffered fragments, ONE barrier + one waitcnt per K-tile.
// XCD mapping: each XCD owns NTILES/8 contiguous m-tiles, nb fast-varying.
// LDS 128KB dynamic: 2 bufs x { A_k0 16K | A_k1 16K | B_k0 16K | B_k1 16K }
// MODE 0: hmid[p,:] = gelu(xb[tok(p),:] @ W1t[e]^T)             (K=1024, N=2048)
// MODE 1: hmid[p,0:1024) = bf16( w(p) * (hmid[p,:] @ W2t[e]^T) ) in-place
//         (block writes only rows it owns; all reads of those rows precede it)
template <int MODE, int K, int N, int NTILES>
__global__ __launch_bounds__(512) void moe_gemm8(
    const unsigned short* __restrict__ A, const unsigned short* __restrict__ Bt,
    const int* __restrict__ pair_token, const float* __restrict__ pair_w,
    const int* __restrict__ tile_expert, int tile_base,
    unsigned short* __restrict__ outbf) {
  constexpr int NBN = N / 256;
  constexpr int NTk = K / 64;
  constexpr int MTC = NTILES / 8;              // m-tiles per XCD
  constexpr int OSTRIDE = (MODE == 0) ? N : K; // output row stride (in-place for MODE 1)
  int l = blockIdx.x;
  int xcd = l & 7, idx = l >> 3;               // assumes HW xcd = blockIdx % 8
  int mt = tile_base + xcd * MTC + idx / NBN;  // m chunked per XCD
  int nb = idx % NBN;                          // n fast-varying among concurrent
  int e = tile_expert[mt];
  if (e < 0) return;
  int m0 = mt << 8, n0 = nb << 8;

  extern __shared__ __align__(16) char smem_raw[];
  unsigned short* lds = (unsigned short*)smem_raw;   // 65536 elems = 128KB

  int tid = threadIdx.x, lane = tid & 63, wid = tid >> 6;
  int wm = wid >> 2, wn = wid & 3;             // 2 x 4 wave grid, wave tile 128x64
  int lo = lane & 15, hi = lane >> 4;
  int sw = (lo >> 1) & 3;
  int xk = (hi ^ sw) * 8;                      // swizzled chunk within 32-elem half-row

  // read bases (element offsets within a buffer)
  int aRB = (wm * 128 + lo) * 32 + xk;         // + mh*2048 + mf*512 ; +8192 for ks1
  int bRB = 16384 + (wn * 64 + lo) * 32 + xk;  // + nf*512 ; +8192 for ks1

  // ---- stage side: thread (wid, j=0/1) owns rows r0, r1; source chunk pre-swizzled
  int r0 = wid * 32 + (lane >> 2);
  int r1 = r0 + 16;
  int csrc = (lane & 3) ^ ((lane >> 3) & 3);   // == (lane&3) ^ ((r>>1)&3), same for r0/r1
  const unsigned short *aB0, *aB1, *bB0, *bB1;
  if (MODE == 0) {
    int t0 = pair_token[m0 + r0]; if (t0 < 0) t0 = 0;
    int t1 = pair_token[m0 + r1]; if (t1 < 0) t1 = 0;
    aB0 = A + (size_t)t0 * K + csrc * 8;
    aB1 = A + (size_t)t1 * K + csrc * 8;
  } else {
    aB0 = A + (size_t)(m0 + r0) * K + csrc * 8;
    aB1 = A + (size_t)(m0 + r1) * K + csrc * 8;
  }
  bB0 = Bt + ((size_t)e * N + n0 + r0) * K + csrc * 8;
  bB1 = Bt + ((size_t)e * N + n0 + r1) * K + csrc * 8;
  int dA = wid * 1024;                         // dest elem base (+ lane*8 implicit)

  // stage whole 64-K-tile s into buffer at elem offset bo (8 gloads)
#define STAGE(s, bo) do { int ko = (s) * 64; \
    gload_lds16(aB0 + ko,      lds + (bo) + dA); \
    gload_lds16(aB1 + ko,      lds + (bo) + dA + 512); \
    gload_lds16(aB0 + ko + 32, lds + (bo) + 8192 + dA); \
    gload_lds16(aB1 + ko + 32, lds + (bo) + 8192 + dA + 512); \
    gload_lds16(bB0 + ko,      lds + (bo) + 16384 + dA); \
    gload_lds16(bB1 + ko,      lds + (bo) + 16384 + dA + 512); \
    gload_lds16(bB0 + ko + 32, lds + (bo) + 24576 + dA); \
    gload_lds16(bB1 + ko + 32, lds + (bo) + 24576 + dA + 512); } while (0)
#define LDS_A(dst, bo, ks) do { _Pragma("unroll") \
    for (int mh = 0; mh < 2; mh++) _Pragma("unroll") \
    for (int mf = 0; mf < 4; mf++) \
      dst[mh * 4 + mf] = *(const bf16x8*)&lds[(bo) + (ks) * 8192 + aRB + mh * 2048 + mf * 512]; } while (0)
#define LDS_B(dst, bo, ks) do { _Pragma("unroll") \
    for (int nf = 0; nf < 4; nf++) \
      dst[nf] = *(const bf16x8*)&lds[(bo) + (ks) * 8192 + bRB + nf * 512]; } while (0)
#define MM32(aq, bq) do { __builtin_amdgcn_s_setprio(1); \
    _Pragma("unroll") for (int m = 0; m < 8; m++) \
    _Pragma("unroll") for (int n = 0; n < 4; n++) \
      acc[m][n] = __builtin_amdgcn_mfma_f32_16x16x32_bf16(bq[n], aq[m], acc[m][n], 0, 0, 0); \
    __builtin_amdgcn_s_setprio(0); } while (0)
#define SYNC() do { \
    asm volatile("s_waitcnt vmcnt(0) lgkmcnt(0)" ::: "memory"); \
    __builtin_amdgcn_sched_barrier(0); \
    asm volatile("s_barrier" ::: "memory"); \
    __builtin_amdgcn_sched_barrier(0); } while (0)

  f32x4 acc[8][4];
#pragma unroll
  for (int i = 0; i < 8; i++)
#pragma unroll
    for (int j = 0; j < 4; j++) acc[i][j] = (f32x4){0.f, 0.f, 0.f, 0.f};

  bf16x8 afrA[8], bfrA[4], afrB[8], bfrB[4];

  // prologue: stage tile0->buf0, tile1->buf1; wait tile0 (8 outstanding = tile1)
  STAGE(0, 0);
  STAGE(1, 32768);
  asm volatile("s_waitcnt vmcnt(8)" ::: "memory");
  __builtin_amdgcn_sched_barrier(0);
  asm volatile("s_barrier" ::: "memory");
  __builtin_amdgcn_sched_barrier(0);
  LDS_A(afrA, 0, 0);
  LDS_B(bfrA, 0, 0);

  for (int t = 0; t < NTk; ++t) {
    int bo = (t & 1) << 15, bn = bo ^ 32768;
    // ds_read (t, ks1) -> regB while MFMA consumes regA (t, ks0)
    LDS_A(afrB, bo, 1);
    LDS_B(bfrB, bo, 1);
    MM32(afrA, bfrA);
    // boundary: my reads of buf[t] done (lgkm), stage(t+1) landed (vm), all waves synced
    SYNC();
    if (t + 2 < NTk) STAGE(t + 2, bo);        // refill freed buffer, full-tile lead
    if (t + 1 < NTk) {                        // ds_read (t+1, ks0) -> regA
      LDS_A(afrA, bn, 0);
      LDS_B(bfrA, bn, 0);
    }
    MM32(afrB, bfrB);                         // (t, ks1); hides regA ds_read latency
  }
  // drain any outstanding global_load_lds before epilogue / endpgm
  asm volatile("s_waitcnt vmcnt(0)" ::: "memory");
  __builtin_amdgcn_sched_barrier(0);
#undef STAGE
#undef LDS_A
#undef LDS_B
#undef MM32
#undef SYNC

#pragma unroll
  for (int mh = 0; mh < 2; mh++)
#pragma unroll
    for (int mf = 0; mf < 4; mf++) {
      size_t p = m0 + wm * 128 + mh * 64 + mf * 16 + lo;
      float w = (MODE == 0) ? 0.f : pair_w[p];
#pragma unroll
      for (int nf = 0; nf < 4; nf++) {
        int f = n0 + wn * 64 + nf * 16 + hi * 4;
        us4 pk;
#pragma unroll
        for (int r = 0; r < 4; r++) {
          float v = acc[mh * 4 + mf][nf][r];
          if (MODE == 0) {
            float u = fmaf(0.044715f * v * v, v, v);
            float s = 1.f / (1.f + __expf(-1.5957691216057308f * u));
            pk[r] = f2bf(v * s);
          } else {
            pk[r] = f2bf(w * v);
          }
        }
        *(us4*)&outbf[p * (size_t)OSTRIDE + f] = pk;
      }
    }
}

// ---------------- combine: out[t] = hout[inv0[t]] + hout[inv1[t]]  (hout = hmid rows)
__global__ __launch_bounds__(256) void combine_kernel(
    const unsigned short* __restrict__ hout, const int* __restrict__ inv0,
    const int* __restrict__ inv1, float* __restrict__ outp) {
  int idx = blockIdx.x * 256 + threadIdx.x;
  int t = idx >> 7;                  // 128 threads per token row
  int c = (idx & 127) * 8;
  int p0 = inv0[t], p1 = inv1[t];
  bf16x8 va = *(const bf16x8*)&hout[(size_t)p0 * F_DIM + c];
  bf16x8 vb = *(const bf16x8*)&hout[(size_t)p1 * F_DIM + c];
  float* orow = outp + (size_t)t * H_DIM + c;
  float4 o0, o1;
  o0.x = bf2f((unsigned short)va[0]) + bf2f((unsigned short)vb[0]);
  o0.y = bf2f((unsigned short)va[1]) + bf2f((unsigned short)vb[1]);
  o0.z = bf2f((unsigned short)va[2]) + bf2f((unsigned short)vb[2]);
  o0.w = bf2f((unsigned short)va[3]) + bf2f((unsigned short)vb[3]);
  o1.x = bf2f((unsigned short)va[4]) + bf2f((unsigned short)vb[4]);
  o1.y = bf2f((unsigned short)va[5]) + bf2f((unsigned short)vb[5]);
  o1.z = bf2f((unsigned short)va[6]) + bf2f((unsigned short)vb[6]);
  o1.w = bf2f((unsigned short)va[7]) + bf2f((unsigned short)vb[7]);
  *(float4*)&orow[0] = o0;
  *(float4*)&orow[4] = o1;
}

__global__ void finalize_kernel(const float* __restrict__ scal,
                                float* __restrict__ outTail) {
  if (threadIdx.x == 0 && blockIdx.x == 0) {
    float invT = 1.f / (float)T_TOKENS;
    outTail[0] = scal[0] * invT;  // z_loss
    float tpe0 = scal[1] * invT, tpe1 = scal[2] * invT;
    float rp0 = scal[3] * invT, rp1 = scal[4] * invT;
    outTail[1] = (tpe0 * rp0 + tpe1 * rp1) * 0.5f * 4.f;  // aux (K=2 one_hot path)
  }
}

extern "C" void kernel_launch(void* const* d_in, const int* in_sizes, int n_in,
                              void* d_out, int out_size, void* d_ws, size_t ws_size,
                              hipStream_t stream) {
  const float* x  = (const float*)d_in[0];
  const float* Wg = (const float*)d_in[1];
  const float* W1 = (const float*)d_in[2];
  const float* W2 = (const float*)d_in[3];
  float* outp = (float*)d_out;

  char* w = (char*)d_ws;
  auto alloc = [&](size_t b) { char* p = w; w += (b + 511) & ~(size_t)511; return p; };
  // meta block: scal (8 f32) @ +0, counts (16 i32) @ +64, cursors (16 i32) @ +128
  char*  meta        = alloc(256);
  float* scal        = (float*)(meta + 0);
  int*   counts      = (int*)(meta + 64);
  int*   cursors     = (int*)(meta + 128);
  int*   po          = (int*)alloc(64);
  int*   tile_expert = (int*)alloc(TOT_T * 4);
  TopK*  topk        = (TopK*)alloc((size_t)T_TOKENS * sizeof(TopK));
  int*   pair_token  = (int*)alloc((size_t)MAX_PAIRS * 4);
  float* pair_w      = (float*)alloc((size_t)MAX_PAIRS * 4);
  int*   inv0        = (int*)alloc((size_t)T_TOKENS * 4);
  int*   inv1        = (int*)alloc((size_t)T_TOKENS * 4);
  // staged buffers padded +512B (staging tail prefetch may touch past end)
  unsigned short* xb   = (unsigned short*)alloc((size_t)T_TOKENS * H_DIM * 2 + 512);
  unsigned short* w1t  = (unsigned short*)alloc((size_t)E_NUM * F_DIM * H_DIM * 2 + 512);
  unsigned short* hmid = (unsigned short*)alloc((size_t)MAX_PAIRS * F_DIM * 2 + 512);
  // try separate w2t (removes W2-transpose from GEMM1->GEMM2 critical path);
  // fall back to aliasing xb if the workspace is too small (~241 MiB needed).
  unsigned short* w2t_sep = (unsigned short*)alloc((size_t)E_NUM * H_DIM * F_DIM * 2 + 512);
  bool sep = ((size_t)(w - (char*)d_ws) <= ws_size);
  unsigned short* w2t = sep ? w2t_sep : xb;

  // allow 128KB dynamic LDS for the GEMM kernels (host-side attr, capture-safe)
  hipFuncSetAttribute((const void*)&moe_gemm8<0, H_DIM, F_DIM, TOT_T>,
                      hipFuncAttributeMaxDynamicSharedMemorySize, 131072);
  hipFuncSetAttribute((const void*)&moe_gemm8<1, F_DIM, H_DIM, TOT_T>,
                      hipFuncAttributeMaxDynamicSharedMemorySize, 131072);

  hipMemsetAsync(meta, 0, 256, stream);
  hipMemsetAsync(pair_token, 0xFF, (size_t)MAX_PAIRS * 4, stream);  // -1

  dim3 b256(256), b512(512);
  // W1 [E][H][F] -> w1t [E][F][H]
  transpose_cast<<<dim3(F_DIM / 64, H_DIM / 64, E_NUM), b256, 0, stream>>>(W1, w1t, H_DIM, F_DIM);
  // W2 [E][F][H] -> w2t [E][H][F] — off the critical path when workspace permits
  if (sep)
    transpose_cast<<<dim3(H_DIM / 64, F_DIM / 64, E_NUM), b256, 0, stream>>>(W2, w2t, F_DIM, H_DIM);
  router_kernel<<<1024, b256, 0, stream>>>(x, Wg, xb, topk, counts, scal);
  scan_kernel<<<1, b256, 0, stream>>>(counts, po, tile_expert);
  assign_kernel<<<T_TOKENS / 256, b256, 0, stream>>>(topk, po, cursors, pair_token, pair_w,
                                                     inv0, inv1);
  // GEMM1: hmid = gelu(gather(xb) @ W1t^T), both rank regions, one dispatch
  moe_gemm8<0, H_DIM, F_DIM, TOT_T><<<dim3((F_DIM / 256) * TOT_T), b512, 131072, stream>>>(
      xb, w1t, pair_token, pair_w, tile_expert, 0, hmid);
  if (!sep)   // aliased path: xb dead only now
    transpose_cast<<<dim3(H_DIM / 64, F_DIM / 64, E_NUM), b256, 0, stream>>>(W2, w2t, F_DIM, H_DIM);
  // GEMM2: ONE dispatch, all 144 m-tiles; writes bf16 w(p)*(hmid[p]@W2t^T)
  // in-place into hmid[p][0:1024) (rows disjoint per block, reads precede writes)
  moe_gemm8<1, F_DIM, H_DIM, TOT_T><<<dim3((H_DIM / 256) * TOT_T), b512, 131072, stream>>>(
      hmid, w2t, pair_token, pair_w, tile_expert, 0, hmid);
  // combine: out[t] = hout[inv0[t]] + hout[inv1[t]]
  combine_kernel<<<dim3(T_TOKENS * 128 / 256), b256, 0, stream>>>(hmid, inv0, inv1, outp);
  finalize_kernel<<<1, 64, 0, stream>>>(scal, outp + (size_t)T_TOKENS * H_DIM);
}

// Round 10
// 641.807 us; speedup vs baseline: 1.1716x; 1.0311x over previous
//
#include <hip/hip_runtime.h>
#include <math.h>

#define T_TOKENS 16384
#define H_DIM 1024
#define F_DIM 2048
#define E_NUM 8
#define TPR 72                      // 256-row tiles per rank (16384/256 + 8 pad)
#define TOT_T (2 * TPR)             // 144
#define MAX_PAIRS (TOT_T * 256)     // 36864

typedef __attribute__((ext_vector_type(8))) short bf16x8;
typedef __attribute__((ext_vector_type(4))) float f32x4;
typedef __attribute__((ext_vector_type(4))) unsigned short us4;

struct TopK { int e0, e1; float w0, w1; };

__device__ __forceinline__ unsigned short f2bf(float f) {
  unsigned int u = __float_as_uint(f);
  u = (u + 0x7fffu + ((u >> 16) & 1u)) >> 16;
  return (unsigned short)u;
}

__device__ __forceinline__ float bf2f(unsigned short u) {
  return __uint_as_float(((unsigned int)u) << 16);
}

__device__ __forceinline__ void gload_lds16(const void* g, void* l) {
  __builtin_amdgcn_global_load_lds(
      (const __attribute__((address_space(1))) void*)g,
      (__attribute__((address_space(3))) void*)l, 16, 0, 0);
}

// ---------------- cast + transpose weights: in [E][R][C] f32 -> out [E][C][R] bf16
__global__ __launch_bounds__(256) void transpose_cast(
    const float* __restrict__ in, unsigned short* __restrict__ out, int R, int C) {
  __shared__ float tile[64][65];
  int e = blockIdx.z;
  int r0 = blockIdx.y * 64, c0 = blockIdx.x * 64;
  int tid = threadIdx.x;
  const float* src = in + ((size_t)e * R + r0) * C + c0;
#pragma unroll
  for (int p = 0; p < 4; p++) {
    int id = p * 256 + tid;
    int row = id >> 4, c4 = (id & 15) * 4;
    float4 v = *(const float4*)&src[(size_t)row * C + c4];
    tile[row][c4 + 0] = v.x; tile[row][c4 + 1] = v.y;
    tile[row][c4 + 2] = v.z; tile[row][c4 + 3] = v.w;
  }
  __syncthreads();
  unsigned short* dst = out + ((size_t)e * C + c0) * R + r0;
#pragma unroll
  for (int p = 0; p < 4; p++) {
    int id = p * 256 + tid;
    int c = id >> 4, r4 = (id & 15) * 4;
    us4 pk;
#pragma unroll
    for (int j = 0; j < 4; j++) pk[j] = f2bf(tile[r4 + j][c]);
    *(us4*)&dst[(size_t)c * R + r4] = pk;
  }
}

// ---------------- router: logits (f32), softmax, top-2, losses, counts, x->bf16
__global__ __launch_bounds__(256) void router_kernel(
    const float* __restrict__ x, const float* __restrict__ Wg,
    unsigned short* __restrict__ xb, TopK* __restrict__ topk,
    int* __restrict__ counts, float* __restrict__ scal) {
  __shared__ float wg[E_NUM][H_DIM];
  __shared__ int cnt[16];
  __shared__ float sred[4][5];
  int tid = threadIdx.x;
  if (tid < 16) cnt[tid] = 0;
  for (int i = tid; i < E_NUM * H_DIM; i += 256) wg[i & 7][i >> 3] = Wg[i];
  __syncthreads();
  int lane = tid & 63, wid = tid >> 6;
  float zacc = 0.f, c0 = 0.f, c1 = 0.f, s0 = 0.f, s1 = 0.f;
  int wgid = blockIdx.x * 4 + wid;
#pragma unroll
  for (int it = 0; it < 4; ++it) {
    int t = wgid + it * 4096;
    const float4* xr = (const float4*)(x + (size_t)t * H_DIM);
    us4* xbr = (us4*)(xb + (size_t)t * H_DIM);
    float l[E_NUM];
#pragma unroll
    for (int e = 0; e < E_NUM; e++) l[e] = 0.f;
#pragma unroll
    for (int i = 0; i < 4; i++) {
      int j = i * 64 + lane;
      float4 v = xr[j];
      us4 pk;
      pk[0] = f2bf(v.x); pk[1] = f2bf(v.y); pk[2] = f2bf(v.z); pk[3] = f2bf(v.w);
      xbr[j] = pk;
      int h = j * 4;
#pragma unroll
      for (int e = 0; e < E_NUM; e++) {
        const f32x4 wv = *(const f32x4*)&wg[e][h];
        l[e] = fmaf(v.x, wv[0], l[e]);
        l[e] = fmaf(v.y, wv[1], l[e]);
        l[e] = fmaf(v.z, wv[2], l[e]);
        l[e] = fmaf(v.w, wv[3], l[e]);
      }
    }
#pragma unroll
    for (int off = 32; off > 0; off >>= 1) {
#pragma unroll
      for (int e = 0; e < E_NUM; e++) l[e] += __shfl_xor(l[e], off, 64);
    }
    if (lane == 0) {
      float mx = l[0];
#pragma unroll
      for (int e = 1; e < E_NUM; e++) mx = fmaxf(mx, l[e]);
      float p[E_NUM]; float se = 0.f;
#pragma unroll
      for (int e = 0; e < E_NUM; e++) { p[e] = expf(l[e] - mx); se += p[e]; }
      float logz = logf(se) + mx;
      int e0 = 0; float b0 = p[0];
#pragma unroll
      for (int e = 1; e < E_NUM; e++) if (p[e] > b0) { b0 = p[e]; e0 = e; }
      int e1 = -1; float b1 = -1.f;
#pragma unroll
      for (int e = 0; e < E_NUM; e++) if (e != e0 && p[e] > b1) { b1 = p[e]; e1 = e; }
      float w0 = b0 / se, w1 = b1 / se;
      TopK tk; tk.e0 = e0; tk.e1 = e1; tk.w0 = w0; tk.w1 = w1;
      topk[t] = tk;
      atomicAdd(&cnt[e0], 1);
      atomicAdd(&cnt[8 + e1], 1);
      zacc += logz * logz;
      c0 += (e0 == 0 || e1 == 0) ? 1.f : 0.f;
      c1 += (e0 == 1 || e1 == 1) ? 1.f : 0.f;
      s0 += w0; s1 += w1;
    }
  }
  if (lane == 0) {
    sred[wid][0] = zacc; sred[wid][1] = c0; sred[wid][2] = c1;
    sred[wid][3] = s0;   sred[wid][4] = s1;
  }
  __syncthreads();
  if (tid == 0) {
    float a[5] = {0.f, 0.f, 0.f, 0.f, 0.f};
    for (int w2 = 0; w2 < 4; w2++)
      for (int k = 0; k < 5; k++) a[k] += sred[w2][k];
    for (int k = 0; k < 5; k++) atomicAdd(&scal[k], a[k]);
  }
  if (tid < 16 && cnt[tid]) atomicAdd(&counts[tid], cnt[tid]);
}

// ---------------- offsets padded to 256 rows per (rank, expert) — parallel version
__global__ __launch_bounds__(256) void scan_kernel(
    const int* __restrict__ counts, int* __restrict__ po,
    int* __restrict__ tile_expert) {
  __shared__ int nt[16], start[16];
  int tid = threadIdx.x;
  if (tid < 16) {
    int r = tid >> 3, e = tid & 7;
    int s = 0;
    for (int j = 0; j < e; j++) s += (counts[(r << 3) + j] + 255) >> 8;
    nt[tid] = (counts[tid] + 255) >> 8;
    start[tid] = s;
    po[tid] = r * TPR * 256 + (s << 8);
  }
  __syncthreads();
  for (int ti = tid; ti < TOT_T; ti += 256) {
    int r = ti / TPR, local = ti % TPR;
    int ex = -1;
#pragma unroll
    for (int e = 0; e < E_NUM; e++) {
      int k = (r << 3) + e;
      if (local >= start[k] && local < start[k] + nt[k]) ex = e;
    }
    tile_expert[ti] = ex;
  }
}

__global__ __launch_bounds__(256) void assign_kernel(
    const TopK* __restrict__ topk, const int* __restrict__ po,
    int* __restrict__ cursors, int* __restrict__ pair_token,
    float* __restrict__ pair_w, int* __restrict__ inv0, int* __restrict__ inv1) {
  int t = blockIdx.x * 256 + threadIdx.x;
  if (t >= T_TOKENS) return;
  TopK tk = topk[t];
  int p0 = po[tk.e0] + atomicAdd(&cursors[tk.e0], 1);
  pair_token[p0] = t; pair_w[p0] = tk.w0; inv0[t] = p0;
  int p1 = po[8 + tk.e1] + atomicAdd(&cursors[8 + tk.e1], 1);
  pair_token[p1] = t; pair_w[p1] = tk.w1; inv1[t] = p1;
}

// ---------------- grouped GEMM, 256x256 tile, 8 waves, m201-style 8-phase schedule
// 8 phases cover 2 K-tiles (BK=64 each). Phase = {ds_read quadrant || stage one
// 16KB half-tile -> barrier -> lgkmcnt(0) -> setprio 16 MFMA -> barrier}.
// vmcnt(6) only at phases 4 and 8 (3 half-tiles x 2 loads in flight). 2 LDS bufs:
// buf0 = even tiles, buf1 = odd. Region deaths (quadrant order Q00,Q01,Q11,Q10):
// A0@P1,B1@P2,A1@P3,B0@P4 -> each phase stages the half that died one phase ago.
// LDS per buf (elems): A0[128r'x64k]@0, A1@8192, B0@16384+0, B1@16384+8192.
// MODE 0: hmid[p,:] = gelu(xb[tok(p),:] @ W1t[e]^T)             (K=1024, N=2048)
// MODE 1: hmid[p,0:1024) = bf16( w(p) * (hmid[p,:] @ W2t[e]^T) ) in-place
template <int MODE, int K, int N, int NTILES>
__global__ __launch_bounds__(512) void moe_gemm8(
    const unsigned short* __restrict__ A, const unsigned short* __restrict__ Bt,
    const int* __restrict__ pair_token, const float* __restrict__ pair_w,
    const int* __restrict__ tile_expert, int tile_base,
    unsigned short* __restrict__ outbf) {
  constexpr int NBN = N / 256;
  constexpr int NTk = K / 64;
  constexpr int MTC = NTILES / 8;              // m-tiles per XCD
  constexpr int OSTRIDE = (MODE == 0) ? N : K; // output row stride (in-place for MODE 1)
  int l = blockIdx.x;
  int xcd = l & 7, idx = l >> 3;               // assumes HW xcd = blockIdx % 8
  int mt = tile_base + xcd * MTC + idx / NBN;  // m chunked per XCD
  int nb = idx % NBN;                          // n fast-varying among concurrent
  int e = tile_expert[mt];
  if (e < 0) return;
  int m0 = mt << 8, n0 = nb << 8;

  extern __shared__ __align__(16) char smem_raw[];
  unsigned short* lds = (unsigned short*)smem_raw;   // 65536 elems = 128KB

  int tid = threadIdx.x, lane = tid & 63, wid = tid >> 6;
  int wm = wid >> 2, wn = wid & 3;             // 2 x 4 wave grid, wave tile 128x64
  int lo = lane & 15, hi = lane >> 4;
  int l7 = lane & 7;

  // ---- read-side bases (elem offsets within a buffer) ----
  int aRB = (wm * 64 + lo) * 64;               // + qa*8192 + mf*1024 + kd
  int bRB = (wn * 32 + lo) * 64;               // + 16384 + qb*8192 + nf*1024 + kd
  int kd0 = (hi ^ l7) * 8;                     // swizzled chunk, ks=0
  int kd1 = ((4 + hi) ^ l7) * 8;               // ks=1

  // ---- stage-side: thread tid owns chunks tid (j=0) and tid+512 (j=1) per half
  int kcs = ((tid & 7) ^ ((tid >> 3) & 7)) * 8;  // pre-swizzled source chunk (elems)
  int rr = tid >> 3;                             // 0..63
  const unsigned short *aSrc[2][2], *bSrc[2][2];
#pragma unroll
  for (int qa = 0; qa < 2; qa++)
#pragma unroll
    for (int j = 0; j < 2; j++) {
      int row = j * 128 + qa * 64 + rr;
      size_t off;
      if (MODE == 0) {
        int tk = pair_token[m0 + row]; if (tk < 0) tk = 0;
        off = (size_t)tk * K;
      } else {
        off = (size_t)(m0 + row) * K;
      }
      aSrc[qa][j] = A + off + kcs;
    }
#pragma unroll
  for (int qb = 0; qb < 2; qb++)
#pragma unroll
    for (int j = 0; j < 2; j++) {
      int rp = j * 64 + rr;
      int col = (rp >> 5) * 64 + qb * 32 + (rp & 31);
      bSrc[qb][j] = Bt + ((size_t)e * N + n0 + col) * K + kcs;
    }

#define ST_A(qa, s, sb) do { if ((s) < NTk) { \
    gload_lds16(aSrc[qa][0] + (size_t)(s) * 64, lds + (sb) + (qa) * 8192 + wid * 512); \
    gload_lds16(aSrc[qa][1] + (size_t)(s) * 64, lds + (sb) + (qa) * 8192 + 4096 + wid * 512); } } while (0)
#define ST_B(qb, s, sb) do { if ((s) < NTk) { \
    gload_lds16(bSrc[qb][0] + (size_t)(s) * 64, lds + (sb) + 16384 + (qb) * 8192 + wid * 512); \
    gload_lds16(bSrc[qb][1] + (size_t)(s) * 64, lds + (sb) + 16384 + (qb) * 8192 + 4096 + wid * 512); } } while (0)
#define RD_A(qa, rb) do { _Pragma("unroll") \
    for (int mf = 0; mf < 4; mf++) { \
      afr[mf * 2 + 0] = *(const bf16x8*)&lds[(rb) + (qa) * 8192 + aRB + mf * 1024 + kd0]; \
      afr[mf * 2 + 1] = *(const bf16x8*)&lds[(rb) + (qa) * 8192 + aRB + mf * 1024 + kd1]; } } while (0)
#define RD_B(qb, rb) do { _Pragma("unroll") \
    for (int nf = 0; nf < 2; nf++) { \
      bfr[nf * 2 + 0] = *(const bf16x8*)&lds[(rb) + 16384 + (qb) * 8192 + bRB + nf * 1024 + kd0]; \
      bfr[nf * 2 + 1] = *(const bf16x8*)&lds[(rb) + 16384 + (qb) * 8192 + bRB + nf * 1024 + kd1]; } } while (0)
#define MMQ(qa, qb) do { _Pragma("unroll") \
    for (int mf = 0; mf < 4; mf++) _Pragma("unroll") \
    for (int nf = 0; nf < 2; nf++) { \
      acc[(qa) * 4 + mf][(qb) * 2 + nf] = __builtin_amdgcn_mfma_f32_16x16x32_bf16( \
          bfr[nf * 2 + 0], afr[mf * 2 + 0], acc[(qa) * 4 + mf][(qb) * 2 + nf], 0, 0, 0); \
      acc[(qa) * 4 + mf][(qb) * 2 + nf] = __builtin_amdgcn_mfma_f32_16x16x32_bf16( \
          bfr[nf * 2 + 1], afr[mf * 2 + 1], acc[(qa) * 4 + mf][(qb) * 2 + nf], 0, 0, 0); } } while (0)
#define PH_TAIL(QA, QB) do { \
    __builtin_amdgcn_s_barrier(); \
    asm volatile("s_waitcnt lgkmcnt(0)" ::: "memory"); \
    __builtin_amdgcn_s_setprio(1); \
    MMQ(QA, QB); \
    __builtin_amdgcn_s_setprio(0); \
    __builtin_amdgcn_s_barrier(); } while (0)

  f32x4 acc[8][4];
#pragma unroll
  for (int i = 0; i < 8; i++)
#pragma unroll
    for (int j = 0; j < 4; j++) acc[i][j] = (f32x4){0.f, 0.f, 0.f, 0.f};

  bf16x8 afr[8], bfr[4];

  // prologue: tile0 complete + tile1 {A0,B1,A1}; B0(1) staged at first P1.
  ST_A(0, 0, 0); ST_B(0, 0, 0); ST_B(1, 0, 0); ST_A(1, 0, 0);
  ST_A(0, 1, 32768); ST_B(1, 1, 32768); ST_A(1, 1, 32768);
  asm volatile("s_waitcnt vmcnt(0)" ::: "memory");
  __builtin_amdgcn_s_barrier();

  for (int it = 0; it < NTk / 2; ++it) {
    int t = it * 2;
    // ---- P1: reads A0,B0(t)[buf0]; stage B0(t+1)->buf1 ----
    RD_A(0, 0); RD_B(0, 0);
    ST_B(0, t + 1, 32768);
    asm volatile("s_waitcnt lgkmcnt(8)" ::: "memory");
    PH_TAIL(0, 0);
    // ---- P2: reads B1(t); stage A0(t+2)->buf0 (A0 died @P1) ----
    RD_B(1, 0);
    ST_A(0, t + 2, 0);
    PH_TAIL(0, 1);
    // ---- P3: reads A1(t); stage B1(t+2) (died @P2) ----
    RD_A(1, 0);
    ST_B(1, t + 2, 0);
    PH_TAIL(1, 1);
    // ---- P4: re-reads B0(t); stage A1(t+2) (died @P3); vmcnt(6) ----
    RD_B(0, 0);
    ST_A(1, t + 2, 0);
    asm volatile("s_waitcnt vmcnt(6)" ::: "memory");
    PH_TAIL(1, 0);
    // ---- P5: reads A0,B0(t+1)[buf1]; stage B0(t+2)->buf0 (died @P4) ----
    RD_A(0, 32768); RD_B(0, 32768);
    ST_B(0, t + 2, 0);
    asm volatile("s_waitcnt lgkmcnt(8)" ::: "memory");
    PH_TAIL(0, 0);
    // ---- P6: reads B1(t+1); stage A0(t+3)->buf1 ----
    RD_B(1, 32768);
    ST_A(0, t + 3, 32768);
    PH_TAIL(0, 1);
    // ---- P7: reads A1(t+1); stage B1(t+3) ----
    RD_A(1, 32768);
    ST_B(1, t + 3, 32768);
    PH_TAIL(1, 1);
    // ---- P8: re-reads B0(t+1); stage A1(t+3); vmcnt(6) ----
    RD_B(0, 32768);
    ST_A(1, t + 3, 32768);
    asm volatile("s_waitcnt vmcnt(6)" ::: "memory");
    PH_TAIL(1, 0);
  }
  // drain all outstanding global_load_lds before epilogue / endpgm
  asm volatile("s_waitcnt vmcnt(0)" ::: "memory");
#undef ST_A
#undef ST_B
#undef RD_A
#undef RD_B
#undef MMQ
#undef PH_TAIL

#pragma unroll
  for (int mh = 0; mh < 2; mh++)
#pragma unroll
    for (int mf = 0; mf < 4; mf++) {
      size_t p = m0 + wm * 128 + mh * 64 + mf * 16 + lo;
      float w = (MODE == 0) ? 0.f : pair_w[p];
#pragma unroll
      for (int nf = 0; nf < 4; nf++) {
        int f = n0 + wn * 64 + nf * 16 + hi * 4;
        us4 pk;
#pragma unroll
        for (int r = 0; r < 4; r++) {
          float v = acc[mh * 4 + mf][nf][r];
          if (MODE == 0) {
            float u = fmaf(0.044715f * v * v, v, v);
            float s = 1.f / (1.f + __expf(-1.5957691216057308f * u));
            pk[r] = f2bf(v * s);
          } else {
            pk[r] = f2bf(w * v);
          }
        }
        *(us4*)&outbf[p * (size_t)OSTRIDE + f] = pk;
      }
    }
}

// ---------------- combine: out[t] = hout[inv0[t]] + hout[inv1[t]]  (hout = hmid rows)
__global__ __launch_bounds__(256) void combine_kernel(
    const unsigned short* __restrict__ hout, const int* __restrict__ inv0,
    const int* __restrict__ inv1, float* __restrict__ outp) {
  int idx = blockIdx.x * 256 + threadIdx.x;
  int t = idx >> 7;                  // 128 threads per token row
  int c = (idx & 127) * 8;
  int p0 = inv0[t], p1 = inv1[t];
  bf16x8 va = *(const bf16x8*)&hout[(size_t)p0 * F_DIM + c];
  bf16x8 vb = *(const bf16x8*)&hout[(size_t)p1 * F_DIM + c];
  float* orow = outp + (size_t)t * H_DIM + c;
  float4 o0, o1;
  o0.x = bf2f((unsigned short)va[0]) + bf2f((unsigned short)vb[0]);
  o0.y = bf2f((unsigned short)va[1]) + bf2f((unsigned short)vb[1]);
  o0.z = bf2f((unsigned short)va[2]) + bf2f((unsigned short)vb[2]);
  o0.w = bf2f((unsigned short)va[3]) + bf2f((unsigned short)vb[3]);
  o1.x = bf2f((unsigned short)va[4]) + bf2f((unsigned short)vb[4]);
  o1.y = bf2f((unsigned short)va[5]) + bf2f((unsigned short)vb[5]);
  o1.z = bf2f((unsigned short)va[6]) + bf2f((unsigned short)vb[6]);
  o1.w = bf2f((unsigned short)va[7]) + bf2f((unsigned short)vb[7]);
  *(float4*)&orow[0] = o0;
  *(float4*)&orow[4] = o1;
}

__global__ void finalize_kernel(const float* __restrict__ scal,
                                float* __restrict__ outTail) {
  if (threadIdx.x == 0 && blockIdx.x == 0) {
    float invT = 1.f / (float)T_TOKENS;
    outTail[0] = scal[0] * invT;  // z_loss
    float tpe0 = scal[1] * invT, tpe1 = scal[2] * invT;
    float rp0 = scal[3] * invT, rp1 = scal[4] * invT;
    outTail[1] = (tpe0 * rp0 + tpe1 * rp1) * 0.5f * 4.f;  // aux (K=2 one_hot path)
  }
}

extern "C" void kernel_launch(void* const* d_in, const int* in_sizes, int n_in,
                              void* d_out, int out_size, void* d_ws, size_t ws_size,
                              hipStream_t stream) {
  const float* x  = (const float*)d_in[0];
  const float* Wg = (const float*)d_in[1];
  const float* W1 = (const float*)d_in[2];
  const float* W2 = (const float*)d_in[3];
  float* outp = (float*)d_out;

  char* w = (char*)d_ws;
  auto alloc = [&](size_t b) { char* p = w; w += (b + 511) & ~(size_t)511; return p; };
  // meta block: scal (8 f32) @ +0, counts (16 i32) @ +64, cursors (16 i32) @ +128
  char*  meta        = alloc(256);
  float* scal        = (float*)(meta + 0);
  int*   counts      = (int*)(meta + 64);
  int*   cursors     = (int*)(meta + 128);
  int*   po          = (int*)alloc(64);
  int*   tile_expert = (int*)alloc(TOT_T * 4);
  TopK*  topk        = (TopK*)alloc((size_t)T_TOKENS * sizeof(TopK));
  int*   pair_token  = (int*)alloc((size_t)MAX_PAIRS * 4);
  float* pair_w      = (float*)alloc((size_t)MAX_PAIRS * 4);
  int*   inv0        = (int*)alloc((size_t)T_TOKENS * 4);
  int*   inv1        = (int*)alloc((size_t)T_TOKENS * 4);
  // staged buffers padded +512B (staging tail prefetch may touch past end)
  unsigned short* xb   = (unsigned short*)alloc((size_t)T_TOKENS * H_DIM * 2 + 512);
  unsigned short* w1t  = (unsigned short*)alloc((size_t)E_NUM * F_DIM * H_DIM * 2 + 512);
  unsigned short* hmid = (unsigned short*)alloc((size_t)MAX_PAIRS * F_DIM * 2 + 512);
  // try separate w2t (removes W2-transpose from GEMM1->GEMM2 critical path);
  // fall back to aliasing xb if the workspace is too small (~241 MiB needed).
  unsigned short* w2t_sep = (unsigned short*)alloc((size_t)E_NUM * H_DIM * F_DIM * 2 + 512);
  bool sep = ((size_t)(w - (char*)d_ws) <= ws_size);
  unsigned short* w2t = sep ? w2t_sep : xb;

  // allow 128KB dynamic LDS for the GEMM kernels (host-side attr, capture-safe)
  hipFuncSetAttribute((const void*)&moe_gemm8<0, H_DIM, F_DIM, TOT_T>,
                      hipFuncAttributeMaxDynamicSharedMemorySize, 131072);
  hipFuncSetAttribute((const void*)&moe_gemm8<1, F_DIM, H_DIM, TOT_T>,
                      hipFuncAttributeMaxDynamicSharedMemorySize, 131072);

  hipMemsetAsync(meta, 0, 256, stream);
  hipMemsetAsync(pair_token, 0xFF, (size_t)MAX_PAIRS * 4, stream);  // -1

  dim3 b256(256), b512(512);
  // W1 [E][H][F] -> w1t [E][F][H]
  transpose_cast<<<dim3(F_DIM / 64, H_DIM / 64, E_NUM), b256, 0, stream>>>(W1, w1t, H_DIM, F_DIM);
  // W2 [E][F][H] -> w2t [E][H][F] — off the critical path when workspace permits
  if (sep)
    transpose_cast<<<dim3(H_DIM / 64, F_DIM / 64, E_NUM), b256, 0, stream>>>(W2, w2t, F_DIM, H_DIM);
  router_kernel<<<1024, b256, 0, stream>>>(x, Wg, xb, topk, counts, scal);
  scan_kernel<<<1, b256, 0, stream>>>(counts, po, tile_expert);
  assign_kernel<<<T_TOKENS / 256, b256, 0, stream>>>(topk, po, cursors, pair_token, pair_w,
                                                     inv0, inv1);
  // GEMM1: hmid = gelu(gather(xb) @ W1t^T), both rank regions, one dispatch
  moe_gemm8<0, H_DIM, F_DIM, TOT_T><<<dim3((F_DIM / 256) * TOT_T), b512, 131072, stream>>>(
      xb, w1t, pair_token, pair_w, tile_expert, 0, hmid);
  if (!sep)   // aliased path: xb dead only now
    transpose_cast<<<dim3(H_DIM / 64, F_DIM / 64, E_NUM), b256, 0, stream>>>(W2, w2t, F_DIM, H_DIM);
  // GEMM2: ONE dispatch, all 144 m-tiles; writes bf16 w(p)*(hmid[p]@W2t^T)
  // in-place into hmid[p][0:1024) (rows disjoint per block, reads precede writes)
  moe_gemm8<1, F_DIM, H_DIM, TOT_T><<<dim3((H_DIM / 256) * TOT_T), b512, 131072, stream>>>(
      hmid, w2t, pair_token, pair_w, tile_expert, 0, hmid);
  // combine: out[t] = hout[inv0[t]] + hout[inv1[t]]
  combine_kernel<<<dim3(T_TOKENS * 128 / 256), b256, 0, stream>>>(hmid, inv0, inv1, outp);
  finalize_kernel<<<1, 64, 0, stream>>>(scal, outp + (size_t)T_TOKENS * H_DIM);
}

// Round 11
// 612.171 us; speedup vs baseline: 1.2283x; 1.0484x over previous
//
#include <hip/hip_runtime.h>
#include <math.h>

#define T_TOKENS 16384
#define H_DIM 1024
#define F_DIM 2048
#define E_NUM 8
#define TPR 72                      // 256-row tiles per rank (16384/256 + 8 pad)
#define TOT_T (2 * TPR)             // 144
#define MAX_PAIRS (TOT_T * 256)     // 36864

typedef __attribute__((ext_vector_type(8))) short bf16x8;
typedef __attribute__((ext_vector_type(4))) float f32x4;
typedef __attribute__((ext_vector_type(4))) unsigned short us4;

struct TopK { int e0, e1; float w0, w1; };

__device__ __forceinline__ unsigned short f2bf(float f) {
  unsigned int u = __float_as_uint(f);
  u = (u + 0x7fffu + ((u >> 16) & 1u)) >> 16;
  return (unsigned short)u;
}

__device__ __forceinline__ float bf2f(unsigned short u) {
  return __uint_as_float(((unsigned int)u) << 16);
}

__device__ __forceinline__ void gload_lds16(const void* g, void* l) {
  __builtin_amdgcn_global_load_lds(
      (const __attribute__((address_space(1))) void*)g,
      (__attribute__((address_space(3))) void*)l, 16, 0, 0);
}

// ---------------- cast + transpose weights: in [E][R][C] f32 -> out [E][C][R] bf16
__global__ __launch_bounds__(256) void transpose_cast(
    const float* __restrict__ in, unsigned short* __restrict__ out, int R, int C) {
  __shared__ float tile[64][65];
  int e = blockIdx.z;
  int r0 = blockIdx.y * 64, c0 = blockIdx.x * 64;
  int tid = threadIdx.x;
  const float* src = in + ((size_t)e * R + r0) * C + c0;
#pragma unroll
  for (int p = 0; p < 4; p++) {
    int id = p * 256 + tid;
    int row = id >> 4, c4 = (id & 15) * 4;
    float4 v = *(const float4*)&src[(size_t)row * C + c4];
    tile[row][c4 + 0] = v.x; tile[row][c4 + 1] = v.y;
    tile[row][c4 + 2] = v.z; tile[row][c4 + 3] = v.w;
  }
  __syncthreads();
  unsigned short* dst = out + ((size_t)e * C + c0) * R + r0;
#pragma unroll
  for (int p = 0; p < 4; p++) {
    int id = p * 256 + tid;
    int c = id >> 4, r4 = (id & 15) * 4;
    us4 pk;
#pragma unroll
    for (int j = 0; j < 4; j++) pk[j] = f2bf(tile[r4 + j][c]);
    *(us4*)&dst[(size_t)c * R + r4] = pk;
  }
}

// ---------------- router: logits (f32), softmax, top-2, losses, counts, x->bf16
__global__ __launch_bounds__(256) void router_kernel(
    const float* __restrict__ x, const float* __restrict__ Wg,
    unsigned short* __restrict__ xb, TopK* __restrict__ topk,
    int* __restrict__ counts, float* __restrict__ scal) {
  __shared__ float wg[E_NUM][H_DIM];
  __shared__ int cnt[16];
  __shared__ float sred[4][5];
  int tid = threadIdx.x;
  if (tid < 16) cnt[tid] = 0;
  for (int i = tid; i < E_NUM * H_DIM; i += 256) wg[i & 7][i >> 3] = Wg[i];
  __syncthreads();
  int lane = tid & 63, wid = tid >> 6;
  float zacc = 0.f, c0 = 0.f, c1 = 0.f, s0 = 0.f, s1 = 0.f;
  int wgid = blockIdx.x * 4 + wid;
#pragma unroll
  for (int it = 0; it < 4; ++it) {
    int t = wgid + it * 4096;
    const float4* xr = (const float4*)(x + (size_t)t * H_DIM);
    us4* xbr = (us4*)(xb + (size_t)t * H_DIM);
    float l[E_NUM];
#pragma unroll
    for (int e = 0; e < E_NUM; e++) l[e] = 0.f;
#pragma unroll
    for (int i = 0; i < 4; i++) {
      int j = i * 64 + lane;
      float4 v = xr[j];
      us4 pk;
      pk[0] = f2bf(v.x); pk[1] = f2bf(v.y); pk[2] = f2bf(v.z); pk[3] = f2bf(v.w);
      xbr[j] = pk;
      int h = j * 4;
#pragma unroll
      for (int e = 0; e < E_NUM; e++) {
        const f32x4 wv = *(const f32x4*)&wg[e][h];
        l[e] = fmaf(v.x, wv[0], l[e]);
        l[e] = fmaf(v.y, wv[1], l[e]);
        l[e] = fmaf(v.z, wv[2], l[e]);
        l[e] = fmaf(v.w, wv[3], l[e]);
      }
    }
#pragma unroll
    for (int off = 32; off > 0; off >>= 1) {
#pragma unroll
      for (int e = 0; e < E_NUM; e++) l[e] += __shfl_xor(l[e], off, 64);
    }
    if (lane == 0) {
      float mx = l[0];
#pragma unroll
      for (int e = 1; e < E_NUM; e++) mx = fmaxf(mx, l[e]);
      float p[E_NUM]; float se = 0.f;
#pragma unroll
      for (int e = 0; e < E_NUM; e++) { p[e] = expf(l[e] - mx); se += p[e]; }
      float logz = logf(se) + mx;
      int e0 = 0; float b0 = p[0];
#pragma unroll
      for (int e = 1; e < E_NUM; e++) if (p[e] > b0) { b0 = p[e]; e0 = e; }
      int e1 = -1; float b1 = -1.f;
#pragma unroll
      for (int e = 0; e < E_NUM; e++) if (e != e0 && p[e] > b1) { b1 = p[e]; e1 = e; }
      float w0 = b0 / se, w1 = b1 / se;
      TopK tk; tk.e0 = e0; tk.e1 = e1; tk.w0 = w0; tk.w1 = w1;
      topk[t] = tk;
      atomicAdd(&cnt[e0], 1);
      atomicAdd(&cnt[8 + e1], 1);
      zacc += logz * logz;
      c0 += (e0 == 0 || e1 == 0) ? 1.f : 0.f;
      c1 += (e0 == 1 || e1 == 1) ? 1.f : 0.f;
      s0 += w0; s1 += w1;
    }
  }
  if (lane == 0) {
    sred[wid][0] = zacc; sred[wid][1] = c0; sred[wid][2] = c1;
    sred[wid][3] = s0;   sred[wid][4] = s1;
  }
  __syncthreads();
  if (tid == 0) {
    float a[5] = {0.f, 0.f, 0.f, 0.f, 0.f};
    for (int w2 = 0; w2 < 4; w2++)
      for (int k = 0; k < 5; k++) a[k] += sred[w2][k];
    for (int k = 0; k < 5; k++) atomicAdd(&scal[k], a[k]);
  }
  if (tid < 16 && cnt[tid]) atomicAdd(&counts[tid], cnt[tid]);
}

// ---------------- offsets padded to 256 rows per (rank, expert) — parallel version
__global__ __launch_bounds__(256) void scan_kernel(
    const int* __restrict__ counts, int* __restrict__ po,
    int* __restrict__ tile_expert) {
  __shared__ int nt[16], start[16];
  int tid = threadIdx.x;
  if (tid < 16) {
    int r = tid >> 3, e = tid & 7;
    int s = 0;
    for (int j = 0; j < e; j++) s += (counts[(r << 3) + j] + 255) >> 8;
    nt[tid] = (counts[tid] + 255) >> 8;
    start[tid] = s;
    po[tid] = r * TPR * 256 + (s << 8);
  }
  __syncthreads();
  for (int ti = tid; ti < TOT_T; ti += 256) {
    int r = ti / TPR, local = ti % TPR;
    int ex = -1;
#pragma unroll
    for (int e = 0; e < E_NUM; e++) {
      int k = (r << 3) + e;
      if (local >= start[k] && local < start[k] + nt[k]) ex = e;
    }
    tile_expert[ti] = ex;
  }
}

__global__ __launch_bounds__(256) void assign_kernel(
    const TopK* __restrict__ topk, const int* __restrict__ po,
    int* __restrict__ cursors, int* __restrict__ pair_token,
    float* __restrict__ pair_w, int* __restrict__ inv0, int* __restrict__ inv1) {
  int t = blockIdx.x * 256 + threadIdx.x;
  if (t >= T_TOKENS) return;
  TopK tk = topk[t];
  int p0 = po[tk.e0] + atomicAdd(&cursors[tk.e0], 1);
  pair_token[p0] = t; pair_w[p0] = tk.w0; inv0[t] = p0;
  int p1 = po[8 + tk.e1] + atomicAdd(&cursors[8 + tk.e1], 1);
  pair_token[p1] = t; pair_w[p1] = tk.w1; inv1[t] = p1;
}

// ---------------- grouped GEMM, 256x256 tile, 8 waves, single-barrier 4-phase loop
// Phase = { ds_read quadrant || stage one region -> [vmcnt(8)] -> barrier -> MFMA }.
// B fragments register-held (bfr0 P1->P4, bfr1 P2->P3); A reloaded (afr: A0 P1-P2,
// A1 P3-P4). Region deaths: A0@P1,B0@P1,B1@P2,A1@P3. Stage-death-(p-2) rule under
// single barrier/phase: stage at p may overwrite regions last READ at <= p-2 (all
// waves' reads of p-1 complete before any wave reaches barrier p). Stages:
// P1:B1(t+1), P2:A1(t+1), P3:A0(t+2), P4:B0(t+2) — every stage >=2 phases after
// death; every read has a >=5-phase staged lead, confirmed by vmcnt(8) @ P1/P3.
// LDS per buf (elems): A0@0, A1@8192, B0@16384, B1@24576; bufs at 0 / 32768.
// MODE 0: hmid[p,:] = gelu(xb[tok(p),:] @ W1t[e]^T)             (K=1024, N=2048)
// MODE 1: hmid[p,0:1024) = bf16( w(p) * (hmid[p,:] @ W2t[e]^T) ) in-place
template <int MODE, int K, int N, int NTILES>
__global__ __launch_bounds__(512) void moe_gemm8(
    const unsigned short* __restrict__ A, const unsigned short* __restrict__ Bt,
    const int* __restrict__ pair_token, const float* __restrict__ pair_w,
    const int* __restrict__ tile_expert, int tile_base,
    unsigned short* __restrict__ outbf) {
  constexpr int NBN = N / 256;
  constexpr int NTk = K / 64;
  constexpr int MTC = NTILES / 8;              // m-tiles per XCD
  constexpr int OSTRIDE = (MODE == 0) ? N : K; // output row stride (in-place for MODE 1)
  int l = blockIdx.x;
  int xcd = l & 7, idx = l >> 3;               // assumes HW xcd = blockIdx % 8
  int mt = tile_base + xcd * MTC + idx / NBN;  // m chunked per XCD
  int nb = idx % NBN;                          // n fast-varying among concurrent
  int e = tile_expert[mt];
  if (e < 0) return;
  int m0 = mt << 8, n0 = nb << 8;

  extern __shared__ __align__(16) char smem_raw[];
  unsigned short* lds = (unsigned short*)smem_raw;   // 65536 elems = 128KB

  int tid = threadIdx.x, lane = tid & 63, wid = tid >> 6;
  int wm = wid >> 2, wn = wid & 3;             // 2 x 4 wave grid, wave tile 128x64
  int lo = lane & 15, hi = lane >> 4;
  int l7 = lane & 7;

  // ---- read-side bases (elem offsets within a buffer) ----
  int aRB = (wm * 64 + lo) * 64;               // + qa*8192 + mf*1024 + kd
  int bRB = (wn * 32 + lo) * 64;               // + 16384 + qb*8192 + nf*1024 + kd
  int kd0 = (hi ^ l7) * 8;                     // swizzled chunk, ks=0
  int kd1 = ((4 + hi) ^ l7) * 8;               // ks=1

  // ---- stage-side: thread tid owns chunks tid (j=0) and tid+512 (j=1) per half
  int kcs = ((tid & 7) ^ ((tid >> 3) & 7)) * 8;  // pre-swizzled source chunk (elems)
  int rr = tid >> 3;                             // 0..63
  const unsigned short *aSrc[2][2], *bSrc[2][2];
#pragma unroll
  for (int qa = 0; qa < 2; qa++)
#pragma unroll
    for (int j = 0; j < 2; j++) {
      int row = j * 128 + qa * 64 + rr;
      size_t off;
      if (MODE == 0) {
        int tk = pair_token[m0 + row]; if (tk < 0) tk = 0;
        off = (size_t)tk * K;
      } else {
        off = (size_t)(m0 + row) * K;
      }
      aSrc[qa][j] = A + off + kcs;
    }
#pragma unroll
  for (int qb = 0; qb < 2; qb++)
#pragma unroll
    for (int j = 0; j < 2; j++) {
      int rp = j * 64 + rr;
      int col = (rp >> 5) * 64 + qb * 32 + (rp & 31);
      bSrc[qb][j] = Bt + ((size_t)e * N + n0 + col) * K + kcs;
    }

#define ST_A(qa, s, sb) do { if ((s) < NTk) { \
    gload_lds16(aSrc[qa][0] + (size_t)(s) * 64, lds + (sb) + (qa) * 8192 + wid * 512); \
    gload_lds16(aSrc[qa][1] + (size_t)(s) * 64, lds + (sb) + (qa) * 8192 + 4096 + wid * 512); } } while (0)
#define ST_B(qb, s, sb) do { if ((s) < NTk) { \
    gload_lds16(bSrc[qb][0] + (size_t)(s) * 64, lds + (sb) + 16384 + (qb) * 8192 + wid * 512); \
    gload_lds16(bSrc[qb][1] + (size_t)(s) * 64, lds + (sb) + 16384 + (qb) * 8192 + 4096 + wid * 512); } } while (0)
#define RD_A(dst, qa, rb) do { _Pragma("unroll") \
    for (int mf = 0; mf < 4; mf++) { \
      dst[mf * 2 + 0] = *(const bf16x8*)&lds[(rb) + (qa) * 8192 + aRB + mf * 1024 + kd0]; \
      dst[mf * 2 + 1] = *(const bf16x8*)&lds[(rb) + (qa) * 8192 + aRB + mf * 1024 + kd1]; } } while (0)
#define RD_B(dst, qb, rb) do { _Pragma("unroll") \
    for (int nf = 0; nf < 2; nf++) { \
      dst[nf * 2 + 0] = *(const bf16x8*)&lds[(rb) + 16384 + (qb) * 8192 + bRB + nf * 1024 + kd0]; \
      dst[nf * 2 + 1] = *(const bf16x8*)&lds[(rb) + 16384 + (qb) * 8192 + bRB + nf * 1024 + kd1]; } } while (0)
#define MMQ(aq, bq, QA, QB) do { __builtin_amdgcn_s_setprio(1); _Pragma("unroll") \
    for (int mf = 0; mf < 4; mf++) _Pragma("unroll") \
    for (int nf = 0; nf < 2; nf++) { \
      acc[(QA) * 4 + mf][(QB) * 2 + nf] = __builtin_amdgcn_mfma_f32_16x16x32_bf16( \
          bq[nf * 2 + 0], aq[mf * 2 + 0], acc[(QA) * 4 + mf][(QB) * 2 + nf], 0, 0, 0); \
      acc[(QA) * 4 + mf][(QB) * 2 + nf] = __builtin_amdgcn_mfma_f32_16x16x32_bf16( \
          bq[nf * 2 + 1], aq[mf * 2 + 1], acc[(QA) * 4 + mf][(QB) * 2 + nf], 0, 0, 0); } \
    __builtin_amdgcn_s_setprio(0); } while (0)
#define PH_BAR() do { asm volatile("s_barrier" ::: "memory"); \
    __builtin_amdgcn_sched_barrier(0); } while (0)
#define VMC(n) do { asm volatile("s_waitcnt vmcnt(" #n ")" ::: "memory"); \
    __builtin_amdgcn_sched_barrier(0); } while (0)

  f32x4 acc[8][4];
#pragma unroll
  for (int i = 0; i < 8; i++)
#pragma unroll
    for (int j = 0; j < 4; j++) acc[i][j] = (f32x4){0.f, 0.f, 0.f, 0.f};

  bf16x8 afr[8], bfr0[4], bfr1[4];

  // prologue: tile0 complete -> buf0; tile1 {A0,B0} -> buf1.
  // vmcnt(4): forces tile0 landed, leaves tile1's 4 loads in flight.
  ST_A(0, 0, 0); ST_B(0, 0, 0); ST_B(1, 0, 0); ST_A(1, 0, 0);
  ST_A(0, 1, 32768); ST_B(0, 1, 32768);
  VMC(4); PH_BAR();

  for (int t = 0; t < NTk; ++t) {
    int bo = (t & 1) << 15, bn = bo ^ 32768;
    // P1: read A0,B0(t); stage B1(t+1)->bn (died t-1.P2); vmcnt(8); bar; Q00
    RD_A(afr, 0, bo);
    RD_B(bfr0, 0, bo);
    ST_B(1, t + 1, bn);
    VMC(8); PH_BAR();
    MMQ(afr, bfr0, 0, 0);
    // P2: read B1(t); stage A1(t+1)->bn (died t-1.P3); bar; Q01
    RD_B(bfr1, 1, bo);
    ST_A(1, t + 1, bn);
    PH_BAR();
    MMQ(afr, bfr1, 0, 1);
    // P3: read A1(t); stage A0(t+2)->bo (died this-tile P1); vmcnt(8); bar; Q11
    RD_A(afr, 1, bo);
    ST_A(0, t + 2, bo);
    VMC(8); PH_BAR();
    MMQ(afr, bfr1, 1, 1);
    // P4: no reads; stage B0(t+2)->bo (died P1); bar; Q10 (regs only)
    ST_B(0, t + 2, bo);
    PH_BAR();
    MMQ(afr, bfr0, 1, 0);
  }
  // drain all outstanding global_load_lds before epilogue / endpgm
  asm volatile("s_waitcnt vmcnt(0)" ::: "memory");
  __builtin_amdgcn_sched_barrier(0);
#undef ST_A
#undef ST_B
#undef RD_A
#undef RD_B
#undef MMQ
#undef PH_BAR
#undef VMC

#pragma unroll
  for (int mh = 0; mh < 2; mh++)
#pragma unroll
    for (int mf = 0; mf < 4; mf++) {
      size_t p = m0 + wm * 128 + mh * 64 + mf * 16 + lo;
      float w = (MODE == 0) ? 0.f : pair_w[p];
#pragma unroll
      for (int nf = 0; nf < 4; nf++) {
        int f = n0 + wn * 64 + nf * 16 + hi * 4;
        us4 pk;
#pragma unroll
        for (int r = 0; r < 4; r++) {
          float v = acc[mh * 4 + mf][nf][r];
          if (MODE == 0) {
            float u = fmaf(0.044715f * v * v, v, v);
            float s = 1.f / (1.f + __expf(-1.5957691216057308f * u));
            pk[r] = f2bf(v * s);
          } else {
            pk[r] = f2bf(w * v);
          }
        }
        *(us4*)&outbf[p * (size_t)OSTRIDE + f] = pk;
      }
    }
}

// ---------------- combine: out[t] = hout[inv0[t]] + hout[inv1[t]]  (hout = hmid rows)
__global__ __launch_bounds__(256) void combine_kernel(
    const unsigned short* __restrict__ hout, const int* __restrict__ inv0,
    const int* __restrict__ inv1, float* __restrict__ outp) {
  int idx = blockIdx.x * 256 + threadIdx.x;
  int t = idx >> 7;                  // 128 threads per token row
  int c = (idx & 127) * 8;
  int p0 = inv0[t], p1 = inv1[t];
  bf16x8 va = *(const bf16x8*)&hout[(size_t)p0 * F_DIM + c];
  bf16x8 vb = *(const bf16x8*)&hout[(size_t)p1 * F_DIM + c];
  float* orow = outp + (size_t)t * H_DIM + c;
  float4 o0, o1;
  o0.x = bf2f((unsigned short)va[0]) + bf2f((unsigned short)vb[0]);
  o0.y = bf2f((unsigned short)va[1]) + bf2f((unsigned short)vb[1]);
  o0.z = bf2f((unsigned short)va[2]) + bf2f((unsigned short)vb[2]);
  o0.w = bf2f((unsigned short)va[3]) + bf2f((unsigned short)vb[3]);
  o1.x = bf2f((unsigned short)va[4]) + bf2f((unsigned short)vb[4]);
  o1.y = bf2f((unsigned short)va[5]) + bf2f((unsigned short)vb[5]);
  o1.z = bf2f((unsigned short)va[6]) + bf2f((unsigned short)vb[6]);
  o1.w = bf2f((unsigned short)va[7]) + bf2f((unsigned short)vb[7]);
  *(float4*)&orow[0] = o0;
  *(float4*)&orow[4] = o1;
}

__global__ void finalize_kernel(const float* __restrict__ scal,
                                float* __restrict__ outTail) {
  if (threadIdx.x == 0 && blockIdx.x == 0) {
    float invT = 1.f / (float)T_TOKENS;
    outTail[0] = scal[0] * invT;  // z_loss
    float tpe0 = scal[1] * invT, tpe1 = scal[2] * invT;
    float rp0 = scal[3] * invT, rp1 = scal[4] * invT;
    outTail[1] = (tpe0 * rp0 + tpe1 * rp1) * 0.5f * 4.f;  // aux (K=2 one_hot path)
  }
}

extern "C" void kernel_launch(void* const* d_in, const int* in_sizes, int n_in,
                              void* d_out, int out_size, void* d_ws, size_t ws_size,
                              hipStream_t stream) {
  const float* x  = (const float*)d_in[0];
  const float* Wg = (const float*)d_in[1];
  const float* W1 = (const float*)d_in[2];
  const float* W2 = (const float*)d_in[3];
  float* outp = (float*)d_out;

  char* w = (char*)d_ws;
  auto alloc = [&](size_t b) { char* p = w; w += (b + 511) & ~(size_t)511; return p; };
  // meta block: scal (8 f32) @ +0, counts (16 i32) @ +64, cursors (16 i32) @ +128
  char*  meta        = alloc(256);
  float* scal        = (float*)(meta + 0);
  int*   counts      = (int*)(meta + 64);
  int*   cursors     = (int*)(meta + 128);
  int*   po          = (int*)alloc(64);
  int*   tile_expert = (int*)alloc(TOT_T * 4);
  TopK*  topk        = (TopK*)alloc((size_t)T_TOKENS * sizeof(TopK));
  int*   pair_token  = (int*)alloc((size_t)MAX_PAIRS * 4);
  float* pair_w      = (float*)alloc((size_t)MAX_PAIRS * 4);
  int*   inv0        = (int*)alloc((size_t)T_TOKENS * 4);
  int*   inv1        = (int*)alloc((size_t)T_TOKENS * 4);
  // staged buffers padded +512B (staging tail prefetch may touch past end)
  unsigned short* xb   = (unsigned short*)alloc((size_t)T_TOKENS * H_DIM * 2 + 512);
  unsigned short* w1t  = (unsigned short*)alloc((size_t)E_NUM * F_DIM * H_DIM * 2 + 512);
  unsigned short* hmid = (unsigned short*)alloc((size_t)MAX_PAIRS * F_DIM * 2 + 512);
  // try separate w2t (removes W2-transpose from GEMM1->GEMM2 critical path);
  // fall back to aliasing xb if the workspace is too small (~241 MiB needed).
  unsigned short* w2t_sep = (unsigned short*)alloc((size_t)E_NUM * H_DIM * F_DIM * 2 + 512);
  bool sep = ((size_t)(w - (char*)d_ws) <= ws_size);
  unsigned short* w2t = sep ? w2t_sep : xb;

  // allow 128KB dynamic LDS for the GEMM kernels (host-side attr, capture-safe)
  hipFuncSetAttribute((const void*)&moe_gemm8<0, H_DIM, F_DIM, TOT_T>,
                      hipFuncAttributeMaxDynamicSharedMemorySize, 131072);
  hipFuncSetAttribute((const void*)&moe_gemm8<1, F_DIM, H_DIM, TOT_T>,
                      hipFuncAttributeMaxDynamicSharedMemorySize, 131072);

  hipMemsetAsync(meta, 0, 256, stream);
  hipMemsetAsync(pair_token, 0xFF, (size_t)MAX_PAIRS * 4, stream);  // -1

  dim3 b256(256), b512(512);
  // W1 [E][H][F] -> w1t [E][F][H]
  transpose_cast<<<dim3(F_DIM / 64, H_DIM / 64, E_NUM), b256, 0, stream>>>(W1, w1t, H_DIM, F_DIM);
  // W2 [E][F][H] -> w2t [E][H][F] — off the critical path when workspace permits
  if (sep)
    transpose_cast<<<dim3(H_DIM / 64, F_DIM / 64, E_NUM), b256, 0, stream>>>(W2, w2t, F_DIM, H_DIM);
  router_kernel<<<1024, b256, 0, stream>>>(x, Wg, xb, topk, counts, scal);
  scan_kernel<<<1, b256, 0, stream>>>(counts, po, tile_expert);
  assign_kernel<<<T_TOKENS / 256, b256, 0, stream>>>(topk, po, cursors, pair_token, pair_w,
                                                     inv0, inv1);
  // GEMM1: hmid = gelu(gather(xb) @ W1t^T), both rank regions, one dispatch
  moe_gemm8<0, H_DIM, F_DIM, TOT_T><<<dim3((F_DIM / 256) * TOT_T), b512, 131072, stream>>>(
      xb, w1t, pair_token, pair_w, tile_expert, 0, hmid);
  if (!sep)   // aliased path: xb dead only now
    transpose_cast<<<dim3(H_DIM / 64, F_DIM / 64, E_NUM), b256, 0, stream>>>(W2, w2t, F_DIM, H_DIM);
  // GEMM2: ONE dispatch, all 144 m-tiles; writes bf16 w(p)*(hmid[p]@W2t^T)
  // in-place into hmid[p][0:1024) (rows disjoint per block, reads precede writes)
  moe_gemm8<1, F_DIM, H_DIM, TOT_T><<<dim3((H_DIM / 256) * TOT_T), b512, 131072, stream>>>(
      hmid, w2t, pair_token, pair_w, tile_expert, 0, hmid);
  // combine: out[t] = hout[inv0[t]] + hout[inv1[t]]
  combine_kernel<<<dim3(T_TOKENS * 128 / 256), b256, 0, stream>>>(hmid, inv0, inv1, outp);
  finalize_kernel<<<1, 64, 0, stream>>>(scal, outp + (size_t)T_TOKENS * H_DIM);
}

// Round 13
// 484.017 us; speedup vs baseline: 1.5535x; 1.2648x over previous
//
#include <hip/hip_runtime.h>
#include <math.h>

#define T_TOKENS 16384
#define H_DIM 1024
#define F_DIM 2048
#define E_NUM 8
#define TPR 72                      // 256-row tiles per rank (16384/256 + 8 pad)
#define TOT_T (2 * TPR)             // 144
#define MAX_PAIRS (TOT_T * 256)     // 36864

typedef __attribute__((ext_vector_type(8))) short bf16x8;
typedef __attribute__((ext_vector_type(4))) float f32x4;
typedef __attribute__((ext_vector_type(4))) unsigned short us4;

struct TopK { int e0, e1; float w0, w1; };

__device__ __forceinline__ unsigned short f2bf(float f) {
  unsigned int u = __float_as_uint(f);
  u = (u + 0x7fffu + ((u >> 16) & 1u)) >> 16;
  return (unsigned short)u;
}

__device__ __forceinline__ float bf2f(unsigned short u) {
  return __uint_as_float(((unsigned int)u) << 16);
}

__device__ __forceinline__ void gload_lds16(const void* g, void* l) {
  __builtin_amdgcn_global_load_lds(
      (const __attribute__((address_space(1))) void*)g,
      (__attribute__((address_space(3))) void*)l, 16, 0, 0);
}

// ---------------- standalone cast+transpose: in [E][R][C] f32 -> out [E][C][R] bf16
__global__ __launch_bounds__(256) void transpose_cast(
    const float* __restrict__ in, unsigned short* __restrict__ out, int R, int C) {
  __shared__ float tile[64][65];
  int e = blockIdx.z;
  int r0 = blockIdx.y * 64, c0 = blockIdx.x * 64;
  int tid = threadIdx.x;
  const float* src = in + ((size_t)e * R + r0) * C + c0;
#pragma unroll
  for (int p = 0; p < 4; p++) {
    int id = p * 256 + tid;
    int row = id >> 4, c4 = (id & 15) * 4;
    float4 v = *(const float4*)&src[(size_t)row * C + c4];
    tile[row][c4 + 0] = v.x; tile[row][c4 + 1] = v.y;
    tile[row][c4 + 2] = v.z; tile[row][c4 + 3] = v.w;
  }
  __syncthreads();
  unsigned short* dst = out + ((size_t)e * C + c0) * R + r0;
#pragma unroll
  for (int p = 0; p < 4; p++) {
    int id = p * 256 + tid;
    int c = id >> 4, r4 = (id & 15) * 4;
    us4 pk;
#pragma unroll
    for (int j = 0; j < 4; j++) pk[j] = f2bf(tile[r4 + j][c]);
    *(us4*)&dst[(size_t)c * R + r4] = pk;
  }
}

// ---------------- fused prep: router (blocks 0..1023) + W1 transpose (1024..5119)
__global__ __launch_bounds__(256) void prep_kernel(
    const float* __restrict__ x, const float* __restrict__ Wg,
    const float* __restrict__ W1, unsigned short* __restrict__ xb,
    unsigned short* __restrict__ w1t, TopK* __restrict__ topk,
    int* __restrict__ counts, float* __restrict__ scal) {
  __shared__ __align__(16) char shraw[E_NUM * H_DIM * 4 + 256];
  int bid = blockIdx.x;
  int tid = threadIdx.x;
  if (bid >= 1024) {
    // -------- W1 transpose role: [E][H][F] -> [E][F][H] (== transpose_cast math)
    float* tile = (float*)shraw;               // [64][65] floats
    int lb = bid - 1024;
    int bx = lb & 31, by = (lb >> 5) & 15, e = lb >> 9;
    int r0 = by * 64, c0 = bx * 64;
    const float* src = W1 + ((size_t)e * H_DIM + r0) * F_DIM + c0;
#pragma unroll
    for (int p = 0; p < 4; p++) {
      int id = p * 256 + tid;
      int row = id >> 4, c4 = (id & 15) * 4;
      float4 v = *(const float4*)&src[(size_t)row * F_DIM + c4];
      tile[row * 65 + c4 + 0] = v.x; tile[row * 65 + c4 + 1] = v.y;
      tile[row * 65 + c4 + 2] = v.z; tile[row * 65 + c4 + 3] = v.w;
    }
    __syncthreads();
    unsigned short* dst = w1t + ((size_t)e * F_DIM + c0) * H_DIM + r0;
#pragma unroll
    for (int p = 0; p < 4; p++) {
      int id = p * 256 + tid;
      int c = id >> 4, r4 = (id & 15) * 4;
      us4 pk;
#pragma unroll
      for (int j = 0; j < 4; j++) pk[j] = f2bf(tile[(r4 + j) * 65 + c]);
      *(us4*)&dst[(size_t)c * H_DIM + r4] = pk;
    }
    return;
  }
  // -------- router role --------
  float (*wg)[H_DIM] = (float(*)[H_DIM])shraw;
  int* cnt = (int*)(shraw + E_NUM * H_DIM * 4);
  float (*sred)[5] = (float(*)[5])(shraw + E_NUM * H_DIM * 4 + 64);
  if (tid < 16) cnt[tid] = 0;
  for (int i = tid; i < E_NUM * H_DIM; i += 256) wg[i & 7][i >> 3] = Wg[i];
  __syncthreads();
  int lane = tid & 63, wid = tid >> 6;
  float zacc = 0.f, c0 = 0.f, c1 = 0.f, s0 = 0.f, s1 = 0.f;
  int wgid = bid * 4 + wid;
#pragma unroll
  for (int it = 0; it < 4; ++it) {
    int t = wgid + it * 4096;
    const float4* xr = (const float4*)(x + (size_t)t * H_DIM);
    us4* xbr = (us4*)(xb + (size_t)t * H_DIM);
    float l[E_NUM];
#pragma unroll
    for (int e = 0; e < E_NUM; e++) l[e] = 0.f;
#pragma unroll
    for (int i = 0; i < 4; i++) {
      int j = i * 64 + lane;
      float4 v = xr[j];
      us4 pk;
      pk[0] = f2bf(v.x); pk[1] = f2bf(v.y); pk[2] = f2bf(v.z); pk[3] = f2bf(v.w);
      xbr[j] = pk;
      int h = j * 4;
#pragma unroll
      for (int e = 0; e < E_NUM; e++) {
        const f32x4 wv = *(const f32x4*)&wg[e][h];
        l[e] = fmaf(v.x, wv[0], l[e]);
        l[e] = fmaf(v.y, wv[1], l[e]);
        l[e] = fmaf(v.z, wv[2], l[e]);
        l[e] = fmaf(v.w, wv[3], l[e]);
      }
    }
#pragma unroll
    for (int off = 32; off > 0; off >>= 1) {
#pragma unroll
      for (int e = 0; e < E_NUM; e++) l[e] += __shfl_xor(l[e], off, 64);
    }
    if (lane == 0) {
      float mx = l[0];
#pragma unroll
      for (int e = 1; e < E_NUM; e++) mx = fmaxf(mx, l[e]);
      float p[E_NUM]; float se = 0.f;
#pragma unroll
      for (int e = 0; e < E_NUM; e++) { p[e] = expf(l[e] - mx); se += p[e]; }
      float logz = logf(se) + mx;
      int e0 = 0; float b0 = p[0];
#pragma unroll
      for (int e = 1; e < E_NUM; e++) if (p[e] > b0) { b0 = p[e]; e0 = e; }
      int e1 = -1; float b1 = -1.f;
#pragma unroll
      for (int e = 0; e < E_NUM; e++) if (e != e0 && p[e] > b1) { b1 = p[e]; e1 = e; }
      float w0 = b0 / se, w1 = b1 / se;
      TopK tk; tk.e0 = e0; tk.e1 = e1; tk.w0 = w0; tk.w1 = w1;
      topk[t] = tk;
      atomicAdd(&cnt[e0], 1);
      atomicAdd(&cnt[8 + e1], 1);
      zacc += logz * logz;
      c0 += (e0 == 0 || e1 == 0) ? 1.f : 0.f;
      c1 += (e0 == 1 || e1 == 1) ? 1.f : 0.f;
      s0 += w0; s1 += w1;
    }
  }
  if (lane == 0) {
    sred[wid][0] = zacc; sred[wid][1] = c0; sred[wid][2] = c1;
    sred[wid][3] = s0;   sred[wid][4] = s1;
  }
  __syncthreads();
  if (tid == 0) {
    float a[5] = {0.f, 0.f, 0.f, 0.f, 0.f};
    for (int w2 = 0; w2 < 4; w2++)
      for (int k = 0; k < 5; k++) a[k] += sred[w2][k];
    for (int k = 0; k < 5; k++) atomicAdd(&scal[k], a[k]);
  }
  if (tid < 16 && cnt[tid]) atomicAdd(&counts[tid], cnt[tid]);
}

// ---------------- offsets padded to 256 rows per (rank, expert)
__global__ __launch_bounds__(256) void scan_kernel(
    const int* __restrict__ counts, int* __restrict__ po,
    int* __restrict__ tile_expert) {
  __shared__ int nt[16], start[16];
  int tid = threadIdx.x;
  if (tid < 16) {
    int r = tid >> 3, e = tid & 7;
    int s = 0;
    for (int j = 0; j < e; j++) s += (counts[(r << 3) + j] + 255) >> 8;
    nt[tid] = (counts[tid] + 255) >> 8;
    start[tid] = s;
    po[tid] = r * TPR * 256 + (s << 8);
  }
  __syncthreads();
  for (int ti = tid; ti < TOT_T; ti += 256) {
    int r = ti / TPR, local = ti % TPR;
    int ex = -1;
#pragma unroll
    for (int e = 0; e < E_NUM; e++) {
      int k = (r << 3) + e;
      if (local >= start[k] && local < start[k] + nt[k]) ex = e;
    }
    tile_expert[ti] = ex;
  }
}

// ---------------- assign with LDS-aggregated cursors (16 global atomics/block)
__global__ __launch_bounds__(256) void assign_kernel(
    const TopK* __restrict__ topk, const int* __restrict__ po,
    int* __restrict__ cursors, int* __restrict__ pair_token,
    float* __restrict__ pair_w, int* __restrict__ inv0, int* __restrict__ inv1) {
  __shared__ int lcnt[16], lbase[16];
  int tid = threadIdx.x;
  if (tid < 16) lcnt[tid] = 0;
  __syncthreads();
  int t = blockIdx.x * 256 + tid;
  TopK tk = topk[t];
  int li0 = atomicAdd(&lcnt[tk.e0], 1);
  int li1 = atomicAdd(&lcnt[8 + tk.e1], 1);
  __syncthreads();
  if (tid < 16) lbase[tid] = lcnt[tid] ? atomicAdd(&cursors[tid], lcnt[tid]) : 0;
  __syncthreads();
  int p0 = po[tk.e0] + lbase[tk.e0] + li0;
  pair_token[p0] = t; pair_w[p0] = tk.w0; inv0[t] = p0;
  int p1 = po[8 + tk.e1] + lbase[8 + tk.e1] + li1;
  pair_token[p1] = t; pair_w[p1] = tk.w1; inv1[t] = p1;
}

// ---------------- grouped GEMM, 256x256 tile, 8 waves, single-barrier 4-phase loop
// (byte-identical to R11 — proven 190us / MfmaUtil 33%)
template <int MODE, int K, int N, int NTILES>
__global__ __launch_bounds__(512) void moe_gemm8(
    const unsigned short* __restrict__ A, const unsigned short* __restrict__ Bt,
    const int* __restrict__ pair_token, const float* __restrict__ pair_w,
    const int* __restrict__ tile_expert, int tile_base,
    unsigned short* __restrict__ outbf) {
  constexpr int NBN = N / 256;
  constexpr int NTk = K / 64;
  constexpr int MTC = NTILES / 8;              // m-tiles per XCD
  constexpr int OSTRIDE = (MODE == 0) ? N : K; // output row stride (in-place for MODE 1)
  int l = blockIdx.x;
  int xcd = l & 7, idx = l >> 3;               // assumes HW xcd = blockIdx % 8
  int mt = tile_base + xcd * MTC + idx / NBN;  // m chunked per XCD
  int nb = idx % NBN;                          // n fast-varying among concurrent
  int e = tile_expert[mt];
  if (e < 0) return;
  int m0 = mt << 8, n0 = nb << 8;

  extern __shared__ __align__(16) char smem_raw[];
  unsigned short* lds = (unsigned short*)smem_raw;   // 65536 elems = 128KB

  int tid = threadIdx.x, lane = tid & 63, wid = tid >> 6;
  int wm = wid >> 2, wn = wid & 3;             // 2 x 4 wave grid, wave tile 128x64
  int lo = lane & 15, hi = lane >> 4;
  int l7 = lane & 7;

  int aRB = (wm * 64 + lo) * 64;               // + qa*8192 + mf*1024 + kd
  int bRB = (wn * 32 + lo) * 64;               // + 16384 + qb*8192 + nf*1024 + kd
  int kd0 = (hi ^ l7) * 8;                     // swizzled chunk, ks=0
  int kd1 = ((4 + hi) ^ l7) * 8;               // ks=1

  int kcs = ((tid & 7) ^ ((tid >> 3) & 7)) * 8;  // pre-swizzled source chunk (elems)
  int rr = tid >> 3;                             // 0..63
  const unsigned short *aSrc[2][2], *bSrc[2][2];
#pragma unroll
  for (int qa = 0; qa < 2; qa++)
#pragma unroll
    for (int j = 0; j < 2; j++) {
      int row = j * 128 + qa * 64 + rr;
      size_t off;
      if (MODE == 0) {
        int tk = pair_token[m0 + row]; if (tk < 0) tk = 0;
        off = (size_t)tk * K;
      } else {
        off = (size_t)(m0 + row) * K;
      }
      aSrc[qa][j] = A + off + kcs;
    }
#pragma unroll
  for (int qb = 0; qb < 2; qb++)
#pragma unroll
    for (int j = 0; j < 2; j++) {
      int rp = j * 64 + rr;
      int col = (rp >> 5) * 64 + qb * 32 + (rp & 31);
      bSrc[qb][j] = Bt + ((size_t)e * N + n0 + col) * K + kcs;
    }

#define ST_A(qa, s, sb) do { if ((s) < NTk) { \
    gload_lds16(aSrc[qa][0] + (size_t)(s) * 64, lds + (sb) + (qa) * 8192 + wid * 512); \
    gload_lds16(aSrc[qa][1] + (size_t)(s) * 64, lds + (sb) + (qa) * 8192 + 4096 + wid * 512); } } while (0)
#define ST_B(qb, s, sb) do { if ((s) < NTk) { \
    gload_lds16(bSrc[qb][0] + (size_t)(s) * 64, lds + (sb) + 16384 + (qb) * 8192 + wid * 512); \
    gload_lds16(bSrc[qb][1] + (size_t)(s) * 64, lds + (sb) + 16384 + (qb) * 8192 + 4096 + wid * 512); } } while (0)
#define RD_A(dst, qa, rb) do { _Pragma("unroll") \
    for (int mf = 0; mf < 4; mf++) { \
      dst[mf * 2 + 0] = *(const bf16x8*)&lds[(rb) + (qa) * 8192 + aRB + mf * 1024 + kd0]; \
      dst[mf * 2 + 1] = *(const bf16x8*)&lds[(rb) + (qa) * 8192 + aRB + mf * 1024 + kd1]; } } while (0)
#define RD_B(dst, qb, rb) do { _Pragma("unroll") \
    for (int nf = 0; nf < 2; nf++) { \
      dst[nf * 2 + 0] = *(const bf16x8*)&lds[(rb) + 16384 + (qb) * 8192 + bRB + nf * 1024 + kd0]; \
      dst[nf * 2 + 1] = *(const bf16x8*)&lds[(rb) + 16384 + (qb) * 8192 + bRB + nf * 1024 + kd1]; } } while (0)
#define MMQ(aq, bq, QA, QB) do { __builtin_amdgcn_s_setprio(1); _Pragma("unroll") \
    for (int mf = 0; mf < 4; mf++) _Pragma("unroll") \
    for (int nf = 0; nf < 2; nf++) { \
      acc[(QA) * 4 + mf][(QB) * 2 + nf] = __builtin_amdgcn_mfma_f32_16x16x32_bf16( \
          bq[nf * 2 + 0], aq[mf * 2 + 0], acc[(QA) * 4 + mf][(QB) * 2 + nf], 0, 0, 0); \
      acc[(QA) * 4 + mf][(QB) * 2 + nf] = __builtin_amdgcn_mfma_f32_16x16x32_bf16( \
          bq[nf * 2 + 1], aq[mf * 2 + 1], acc[(QA) * 4 + mf][(QB) * 2 + nf], 0, 0, 0); } \
    __builtin_amdgcn_s_setprio(0); } while (0)
#define PH_BAR() do { asm volatile("s_barrier" ::: "memory"); \
    __builtin_amdgcn_sched_barrier(0); } while (0)
#define VMC(n) do { asm volatile("s_waitcnt vmcnt(" #n ")" ::: "memory"); \
    __builtin_amdgcn_sched_barrier(0); } while (0)

  f32x4 acc[8][4];
#pragma unroll
  for (int i = 0; i < 8; i++)
#pragma unroll
    for (int j = 0; j < 4; j++) acc[i][j] = (f32x4){0.f, 0.f, 0.f, 0.f};

  bf16x8 afr[8], bfr0[4], bfr1[4];

  // prologue: tile0 complete -> buf0; tile1 {A0,B0} -> buf1.
  ST_A(0, 0, 0); ST_B(0, 0, 0); ST_B(1, 0, 0); ST_A(1, 0, 0);
  ST_A(0, 1, 32768); ST_B(0, 1, 32768);
  VMC(4); PH_BAR();

  for (int t = 0; t < NTk; ++t) {
    int bo = (t & 1) << 15, bn = bo ^ 32768;
    // P1: read A0,B0(t); stage B1(t+1)->bn; vmcnt(8); bar; Q00
    RD_A(afr, 0, bo);
    RD_B(bfr0, 0, bo);
    ST_B(1, t + 1, bn);
    VMC(8); PH_BAR();
    MMQ(afr, bfr0, 0, 0);
    // P2: read B1(t); stage A1(t+1)->bn; bar; Q01
    RD_B(bfr1, 1, bo);
    ST_A(1, t + 1, bn);
    PH_BAR();
    MMQ(afr, bfr1, 0, 1);
    // P3: read A1(t); stage A0(t+2)->bo; vmcnt(8); bar; Q11
    RD_A(afr, 1, bo);
    ST_A(0, t + 2, bo);
    VMC(8); PH_BAR();
    MMQ(afr, bfr1, 1, 1);
    // P4: no reads; stage B0(t+2)->bo; bar; Q10 (regs only)
    ST_B(0, t + 2, bo);
    PH_BAR();
    MMQ(afr, bfr0, 1, 0);
  }
  asm volatile("s_waitcnt vmcnt(0)" ::: "memory");
  __builtin_amdgcn_sched_barrier(0);
#undef ST_A
#undef ST_B
#undef RD_A
#undef RD_B
#undef MMQ
#undef PH_BAR
#undef VMC

#pragma unroll
  for (int mh = 0; mh < 2; mh++)
#pragma unroll
    for (int mf = 0; mf < 4; mf++) {
      size_t p = m0 + wm * 128 + mh * 64 + mf * 16 + lo;
      float w = (MODE == 0) ? 0.f : pair_w[p];
#pragma unroll
      for (int nf = 0; nf < 4; nf++) {
        int f = n0 + wn * 64 + nf * 16 + hi * 4;
        us4 pk;
#pragma unroll
        for (int r = 0; r < 4; r++) {
          float v = acc[mh * 4 + mf][nf][r];
          if (MODE == 0) {
            float u = fmaf(0.044715f * v * v, v, v);
            float s = 1.f / (1.f + __expf(-1.5957691216057308f * u));
            pk[r] = f2bf(v * s);
          } else {
            pk[r] = f2bf(w * v);
          }
        }
        *(us4*)&outbf[p * (size_t)OSTRIDE + f] = pk;
      }
    }
}

// ---------------- combine (+ fused finalize in global idx 0)
__global__ __launch_bounds__(256) void combine_kernel(
    const unsigned short* __restrict__ hout, const int* __restrict__ inv0,
    const int* __restrict__ inv1, float* __restrict__ outp,
    const float* __restrict__ scal) {
  int idx = blockIdx.x * 256 + threadIdx.x;
  int t = idx >> 7;                  // 128 threads per token row
  int c = (idx & 127) * 8;
  int p0 = inv0[t], p1 = inv1[t];
  bf16x8 va = *(const bf16x8*)&hout[(size_t)p0 * F_DIM + c];
  bf16x8 vb = *(const bf16x8*)&hout[(size_t)p1 * F_DIM + c];
  float* orow = outp + (size_t)t * H_DIM + c;
  float4 o0, o1;
  o0.x = bf2f((unsigned short)va[0]) + bf2f((unsigned short)vb[0]);
  o0.y = bf2f((unsigned short)va[1]) + bf2f((unsigned short)vb[1]);
  o0.z = bf2f((unsigned short)va[2]) + bf2f((unsigned short)vb[2]);
  o0.w = bf2f((unsigned short)va[3]) + bf2f((unsigned short)vb[3]);
  o1.x = bf2f((unsigned short)va[4]) + bf2f((unsigned short)vb[4]);
  o1.y = bf2f((unsigned short)va[5]) + bf2f((unsigned short)vb[5]);
  o1.z = bf2f((unsigned short)va[6]) + bf2f((unsigned short)vb[6]);
  o1.w = bf2f((unsigned short)va[7]) + bf2f((unsigned short)vb[7]);
  *(float4*)&orow[0] = o0;
  *(float4*)&orow[4] = o1;
  if (idx == 0) {
    float invT = 1.f / (float)T_TOKENS;
    float* outTail = outp + (size_t)T_TOKENS * H_DIM;
    outTail[0] = scal[0] * invT;  // z_loss
    float tpe0 = scal[1] * invT, tpe1 = scal[2] * invT;
    float rp0 = scal[3] * invT, rp1 = scal[4] * invT;
    outTail[1] = (tpe0 * rp0 + tpe1 * rp1) * 0.5f * 4.f;  // aux (K=2 one_hot path)
  }
}

extern "C" void kernel_launch(void* const* d_in, const int* in_sizes, int n_in,
                              void* d_out, int out_size, void* d_ws, size_t ws_size,
                              hipStream_t stream) {
  const float* x  = (const float*)d_in[0];
  const float* Wg = (const float*)d_in[1];
  const float* W1 = (const float*)d_in[2];
  const float* W2 = (const float*)d_in[3];
  float* outp = (float*)d_out;

  char* w = (char*)d_ws;
  auto alloc = [&](size_t b) { char* p = w; w += (b + 511) & ~(size_t)511; return p; };
  char*  meta        = alloc(256);
  float* scal        = (float*)(meta + 0);
  int*   counts      = (int*)(meta + 64);
  int*   cursors     = (int*)(meta + 128);
  int*   po          = (int*)alloc(64);
  int*   tile_expert = (int*)alloc(TOT_T * 4);
  TopK*  topk        = (TopK*)alloc((size_t)T_TOKENS * sizeof(TopK));
  int*   pair_token  = (int*)alloc((size_t)MAX_PAIRS * 4);
  float* pair_w      = (float*)alloc((size_t)MAX_PAIRS * 4);
  int*   inv0        = (int*)alloc((size_t)T_TOKENS * 4);
  int*   inv1        = (int*)alloc((size_t)T_TOKENS * 4);
  unsigned short* xb   = (unsigned short*)alloc((size_t)T_TOKENS * H_DIM * 2 + 512);
  unsigned short* w1t  = (unsigned short*)alloc((size_t)E_NUM * F_DIM * H_DIM * 2 + 512);
  unsigned short* hmid = (unsigned short*)alloc((size_t)MAX_PAIRS * F_DIM * 2 + 512);
  // w2t ALWAYS aliases xb (xb dead after GEMM1; W2 transposed after GEMM1).
  // Total workspace ~219MB, under the 239.8MB proven-good R3 layout.
  unsigned short* w2t = xb;

  hipFuncSetAttribute((const void*)&moe_gemm8<0, H_DIM, F_DIM, TOT_T>,
                      hipFuncAttributeMaxDynamicSharedMemorySize, 131072);
  hipFuncSetAttribute((const void*)&moe_gemm8<1, F_DIM, H_DIM, TOT_T>,
                      hipFuncAttributeMaxDynamicSharedMemorySize, 131072);

  hipMemsetAsync(meta, 0, 256, stream);
  hipMemsetAsync(pair_token, 0xFF, (size_t)MAX_PAIRS * 4, stream);  // -1

  dim3 b256(256), b512(512);
  // fused prep: router (1024 blocks) + W1 transpose (4096 blocks)
  prep_kernel<<<dim3(5120), b256, 0, stream>>>(x, Wg, W1, xb, w1t, topk, counts, scal);
  scan_kernel<<<1, b256, 0, stream>>>(counts, po, tile_expert);
  assign_kernel<<<T_TOKENS / 256, b256, 0, stream>>>(topk, po, cursors, pair_token, pair_w,
                                                     inv0, inv1);
  // GEMM1: hmid = gelu(gather(xb) @ W1t^T), both rank regions, one dispatch
  moe_gemm8<0, H_DIM, F_DIM, TOT_T><<<dim3((F_DIM / 256) * TOT_T), b512, 131072, stream>>>(
      xb, w1t, pair_token, pair_w, tile_expert, 0, hmid);
  // W2 [E][F][H] -> w2t [E][H][F]  (into xb's space — xb dead now)
  transpose_cast<<<dim3(H_DIM / 64, F_DIM / 64, E_NUM), b256, 0, stream>>>(W2, w2t, F_DIM, H_DIM);
  // GEMM2: ONE dispatch, all 144 m-tiles; writes bf16 w(p)*(hmid[p]@W2t^T)
  // in-place into hmid[p][0:1024) (rows disjoint per block, reads precede writes)
  moe_gemm8<1, F_DIM, H_DIM, TOT_T><<<dim3((H_DIM / 256) * TOT_T), b512, 131072, stream>>>(
      hmid, w2t, pair_token, pair_w, tile_expert, 0, hmid);
  // combine + fused finalize
  combine_kernel<<<dim3(T_TOKENS * 128 / 256), b256, 0, stream>>>(hmid, inv0, inv1, outp, scal);
}

// Round 14
// 472.123 us; speedup vs baseline: 1.5926x; 1.0252x over previous
//
#include <hip/hip_runtime.h>
#include <math.h>

#define T_TOKENS 16384
#define H_DIM 1024
#define F_DIM 2048
#define E_NUM 8
#define TPR 72                      // 256-row tiles per rank (16384/256 + 8 pad)
#define TOT_T (2 * TPR)             // 144
#define MAX_PAIRS (TOT_T * 256)     // 36864

typedef __attribute__((ext_vector_type(8))) short bf16x8;
typedef __attribute__((ext_vector_type(4))) float f32x4;
typedef __attribute__((ext_vector_type(4))) unsigned short us4;

struct TopK { int e0, e1; float w0, w1; };

__device__ __forceinline__ unsigned short f2bf(float f) {
  unsigned int u = __float_as_uint(f);
  u = (u + 0x7fffu + ((u >> 16) & 1u)) >> 16;
  return (unsigned short)u;
}

__device__ __forceinline__ float bf2f(unsigned short u) {
  return __uint_as_float(((unsigned int)u) << 16);
}

__device__ __forceinline__ void gload_lds16(const void* g, void* l) {
  __builtin_amdgcn_global_load_lds(
      (const __attribute__((address_space(1))) void*)g,
      (__attribute__((address_space(3))) void*)l, 16, 0, 0);
}

// ---------------- shared transpose body: in [E][R][C] f32 tile -> out [E][C][R] bf16
__device__ __forceinline__ void transpose_body(
    const float* __restrict__ in, unsigned short* __restrict__ out,
    int R, int C, int bx, int by, int e, float* tile /* [64][65] */) {
  int r0 = by * 64, c0 = bx * 64;
  int tid = threadIdx.x;
  const float* src = in + ((size_t)e * R + r0) * C + c0;
#pragma unroll
  for (int p = 0; p < 4; p++) {
    int id = p * 256 + tid;
    int row = id >> 4, c4 = (id & 15) * 4;
    float4 v = *(const float4*)&src[(size_t)row * C + c4];
    tile[row * 65 + c4 + 0] = v.x; tile[row * 65 + c4 + 1] = v.y;
    tile[row * 65 + c4 + 2] = v.z; tile[row * 65 + c4 + 3] = v.w;
  }
  __syncthreads();
  unsigned short* dst = out + ((size_t)e * C + c0) * R + r0;
#pragma unroll
  for (int p = 0; p < 4; p++) {
    int id = p * 256 + tid;
    int c = id >> 4, r4 = (id & 15) * 4;
    us4 pk;
#pragma unroll
    for (int j = 0; j < 4; j++) pk[j] = f2bf(tile[(r4 + j) * 65 + c]);
    *(us4*)&dst[(size_t)c * R + r4] = pk;
  }
}

// ---------------- fused prep: router (0..1023) + W1T (1024..5119) + W2T (5120..9215)
__global__ __launch_bounds__(256) void prep_kernel(
    const float* __restrict__ x, const float* __restrict__ Wg,
    const float* __restrict__ W1, const float* __restrict__ W2,
    unsigned short* __restrict__ xb, unsigned short* __restrict__ w1t,
    unsigned short* __restrict__ w2t, TopK* __restrict__ topk,
    int* __restrict__ counts, float* __restrict__ scal) {
  __shared__ __align__(16) char shraw[E_NUM * H_DIM * 4 + 256];
  int bid = blockIdx.x;
  int tid = threadIdx.x;
  if (bid >= 1024) {
    float* tile = (float*)shraw;
    if (bid < 5120) {
      int lb = bid - 1024;  // W1 [E][H][F] -> w1t [E][F][H]: R=H, C=F
      transpose_body(W1, w1t, H_DIM, F_DIM, lb & 31, (lb >> 5) & 15, lb >> 9, tile);
    } else {
      int lb = bid - 5120;  // W2 [E][F][H] -> w2t [E][H][F]: R=F, C=H
      transpose_body(W2, w2t, F_DIM, H_DIM, lb & 15, (lb >> 4) & 31, lb >> 9, tile);
    }
    return;
  }
  // -------- router role --------
  float (*wg)[H_DIM] = (float(*)[H_DIM])shraw;
  int* cnt = (int*)(shraw + E_NUM * H_DIM * 4);
  float (*sred)[5] = (float(*)[5])(shraw + E_NUM * H_DIM * 4 + 64);
  if (tid < 16) cnt[tid] = 0;
  for (int i = tid; i < E_NUM * H_DIM; i += 256) wg[i & 7][i >> 3] = Wg[i];
  __syncthreads();
  int lane = tid & 63, wid = tid >> 6;
  float zacc = 0.f, c0 = 0.f, c1 = 0.f, s0 = 0.f, s1 = 0.f;
  int wgid = bid * 4 + wid;
#pragma unroll
  for (int it = 0; it < 4; ++it) {
    int t = wgid + it * 4096;
    const float4* xr = (const float4*)(x + (size_t)t * H_DIM);
    us4* xbr = (us4*)(xb + (size_t)t * H_DIM);
    float l[E_NUM];
#pragma unroll
    for (int e = 0; e < E_NUM; e++) l[e] = 0.f;
#pragma unroll
    for (int i = 0; i < 4; i++) {
      int j = i * 64 + lane;
      float4 v = xr[j];
      us4 pk;
      pk[0] = f2bf(v.x); pk[1] = f2bf(v.y); pk[2] = f2bf(v.z); pk[3] = f2bf(v.w);
      xbr[j] = pk;
      int h = j * 4;
#pragma unroll
      for (int e = 0; e < E_NUM; e++) {
        const f32x4 wv = *(const f32x4*)&wg[e][h];
        l[e] = fmaf(v.x, wv[0], l[e]);
        l[e] = fmaf(v.y, wv[1], l[e]);
        l[e] = fmaf(v.z, wv[2], l[e]);
        l[e] = fmaf(v.w, wv[3], l[e]);
      }
    }
#pragma unroll
    for (int off = 32; off > 0; off >>= 1) {
#pragma unroll
      for (int e = 0; e < E_NUM; e++) l[e] += __shfl_xor(l[e], off, 64);
    }
    if (lane == 0) {
      float mx = l[0];
#pragma unroll
      for (int e = 1; e < E_NUM; e++) mx = fmaxf(mx, l[e]);
      float p[E_NUM]; float se = 0.f;
#pragma unroll
      for (int e = 0; e < E_NUM; e++) { p[e] = expf(l[e] - mx); se += p[e]; }
      float logz = logf(se) + mx;
      int e0 = 0; float b0 = p[0];
#pragma unroll
      for (int e = 1; e < E_NUM; e++) if (p[e] > b0) { b0 = p[e]; e0 = e; }
      int e1 = -1; float b1 = -1.f;
#pragma unroll
      for (int e = 0; e < E_NUM; e++) if (e != e0 && p[e] > b1) { b1 = p[e]; e1 = e; }
      float w0 = b0 / se, w1 = b1 / se;
      TopK tk; tk.e0 = e0; tk.e1 = e1; tk.w0 = w0; tk.w1 = w1;
      topk[t] = tk;
      atomicAdd(&cnt[e0], 1);
      atomicAdd(&cnt[8 + e1], 1);
      zacc += logz * logz;
      c0 += (e0 == 0 || e1 == 0) ? 1.f : 0.f;
      c1 += (e0 == 1 || e1 == 1) ? 1.f : 0.f;
      s0 += w0; s1 += w1;
    }
  }
  if (lane == 0) {
    sred[wid][0] = zacc; sred[wid][1] = c0; sred[wid][2] = c1;
    sred[wid][3] = s0;   sred[wid][4] = s1;
  }
  __syncthreads();
  if (tid == 0) {
    float a[5] = {0.f, 0.f, 0.f, 0.f, 0.f};
    for (int w2 = 0; w2 < 4; w2++)
      for (int k = 0; k < 5; k++) a[k] += sred[w2][k];
    for (int k = 0; k < 5; k++) atomicAdd(&scal[k], a[k]);
  }
  if (tid < 16 && cnt[tid]) atomicAdd(&counts[tid], cnt[tid]);
}

// ---------------- offsets padded to 256 rows per (rank, expert)
__global__ __launch_bounds__(256) void scan_kernel(
    const int* __restrict__ counts, int* __restrict__ po,
    int* __restrict__ tile_expert) {
  __shared__ int nt[16], start[16];
  int tid = threadIdx.x;
  if (tid < 16) {
    int r = tid >> 3, e = tid & 7;
    int s = 0;
    for (int j = 0; j < e; j++) s += (counts[(r << 3) + j] + 255) >> 8;
    nt[tid] = (counts[tid] + 255) >> 8;
    start[tid] = s;
    po[tid] = r * TPR * 256 + (s << 8);
  }
  __syncthreads();
  for (int ti = tid; ti < TOT_T; ti += 256) {
    int r = ti / TPR, local = ti % TPR;
    int ex = -1;
#pragma unroll
    for (int e = 0; e < E_NUM; e++) {
      int k = (r << 3) + e;
      if (local >= start[k] && local < start[k] + nt[k]) ex = e;
    }
    tile_expert[ti] = ex;
  }
}

// ---------------- assign with LDS-aggregated cursors (16 global atomics/block)
__global__ __launch_bounds__(256) void assign_kernel(
    const TopK* __restrict__ topk, const int* __restrict__ po,
    int* __restrict__ cursors, int* __restrict__ pair_token,
    float* __restrict__ pair_w, int* __restrict__ inv0, int* __restrict__ inv1) {
  __shared__ int lcnt[16], lbase[16];
  int tid = threadIdx.x;
  if (tid < 16) lcnt[tid] = 0;
  __syncthreads();
  int t = blockIdx.x * 256 + tid;
  TopK tk = topk[t];
  int li0 = atomicAdd(&lcnt[tk.e0], 1);
  int li1 = atomicAdd(&lcnt[8 + tk.e1], 1);
  __syncthreads();
  if (tid < 16) lbase[tid] = lcnt[tid] ? atomicAdd(&cursors[tid], lcnt[tid]) : 0;
  __syncthreads();
  int p0 = po[tk.e0] + lbase[tk.e0] + li0;
  pair_token[p0] = t; pair_w[p0] = tk.w0; inv0[t] = p0;
  int p1 = po[8 + tk.e1] + lbase[8 + tk.e1] + li1;
  pair_token[p1] = t; pair_w[p1] = tk.w1; inv1[t] = p1;
}

// ---------------- grouped GEMM, 256x256 tile, 8 waves, single-barrier 4-phase loop
// R13 schedule (proven 188us), + unroll-2 (compile-time buffer offsets) and
// pointer-increment staging (no per-phase 64-bit address chains).
template <int MODE, int K, int N, int NTILES>
__global__ __launch_bounds__(512) void moe_gemm8(
    const unsigned short* __restrict__ A, const unsigned short* __restrict__ Bt,
    const int* __restrict__ pair_token, const float* __restrict__ pair_w,
    const int* __restrict__ tile_expert, int tile_base,
    unsigned short* __restrict__ outbf) {
  constexpr int NBN = N / 256;
  constexpr int NTk = K / 64;
  constexpr int MTC = NTILES / 8;              // m-tiles per XCD
  constexpr int OSTRIDE = (MODE == 0) ? N : K; // output row stride (in-place for MODE 1)
  int l = blockIdx.x;
  int xcd = l & 7, idx = l >> 3;               // assumes HW xcd = blockIdx % 8
  int mt = tile_base + xcd * MTC + idx / NBN;  // m chunked per XCD
  int nb = idx % NBN;                          // n fast-varying among concurrent
  int e = tile_expert[mt];
  if (e < 0) return;
  int m0 = mt << 8, n0 = nb << 8;

  extern __shared__ __align__(16) char smem_raw[];
  unsigned short* lds = (unsigned short*)smem_raw;   // 65536 elems = 128KB

  int tid = threadIdx.x, lane = tid & 63, wid = tid >> 6;
  int wm = wid >> 2, wn = wid & 3;             // 2 x 4 wave grid, wave tile 128x64
  int lo = lane & 15, hi = lane >> 4;
  int l7 = lane & 7;

  int aRB = (wm * 64 + lo) * 64;               // + qa*8192 + mf*1024 + kd
  int bRB = (wn * 32 + lo) * 64;               // + 16384 + qb*8192 + nf*1024 + kd
  int kd0 = (hi ^ l7) * 8;                     // swizzled chunk, ks=0
  int kd1 = ((4 + hi) ^ l7) * 8;               // ks=1

  int kcs = ((tid & 7) ^ ((tid >> 3) & 7)) * 8;  // pre-swizzled source chunk (elems)
  int rr = tid >> 3;                             // 0..63
  const unsigned short *aSrc[2][2], *bSrc[2][2];
#pragma unroll
  for (int qa = 0; qa < 2; qa++)
#pragma unroll
    for (int j = 0; j < 2; j++) {
      int row = j * 128 + qa * 64 + rr;
      size_t off;
      if (MODE == 0) {
        int tk = pair_token[m0 + row]; if (tk < 0) tk = 0;
        off = (size_t)tk * K;
      } else {
        off = (size_t)(m0 + row) * K;
      }
      aSrc[qa][j] = A + off + kcs;
    }
#pragma unroll
  for (int qb = 0; qb < 2; qb++)
#pragma unroll
    for (int j = 0; j < 2; j++) {
      int rp = j * 64 + rr;
      int col = (rp >> 5) * 64 + qb * 32 + (rp & 31);
      bSrc[qb][j] = Bt + ((size_t)e * N + n0 + col) * K + kcs;
    }

#define ST0(src, qa, s, sb) do { \
    gload_lds16(src[qa][0] + (size_t)(s) * 64, lds + (sb) + wid * 512); \
    gload_lds16(src[qa][1] + (size_t)(s) * 64, lds + (sb) + 4096 + wid * 512); } while (0)
#define ST_P(ptr, base, g) do { if (g) { \
    gload_lds16(ptr[0], lds + (base) + wid * 512); \
    gload_lds16(ptr[1], lds + (base) + 4096 + wid * 512); \
    ptr[0] += 64; ptr[1] += 64; } } while (0)
#define RD_A(dst, qa, rb) do { _Pragma("unroll") \
    for (int mf = 0; mf < 4; mf++) { \
      dst[mf * 2 + 0] = *(const bf16x8*)&lds[(rb) + (qa) * 8192 + aRB + mf * 1024 + kd0]; \
      dst[mf * 2 + 1] = *(const bf16x8*)&lds[(rb) + (qa) * 8192 + aRB + mf * 1024 + kd1]; } } while (0)
#define RD_B(dst, qb, rb) do { _Pragma("unroll") \
    for (int nf = 0; nf < 2; nf++) { \
      dst[nf * 2 + 0] = *(const bf16x8*)&lds[(rb) + 16384 + (qb) * 8192 + bRB + nf * 1024 + kd0]; \
      dst[nf * 2 + 1] = *(const bf16x8*)&lds[(rb) + 16384 + (qb) * 8192 + bRB + nf * 1024 + kd1]; } } while (0)
#define MMQ(aq, bq, QA, QB) do { __builtin_amdgcn_s_setprio(1); _Pragma("unroll") \
    for (int mf = 0; mf < 4; mf++) _Pragma("unroll") \
    for (int nf = 0; nf < 2; nf++) { \
      acc[(QA) * 4 + mf][(QB) * 2 + nf] = __builtin_amdgcn_mfma_f32_16x16x32_bf16( \
          bq[nf * 2 + 0], aq[mf * 2 + 0], acc[(QA) * 4 + mf][(QB) * 2 + nf], 0, 0, 0); \
      acc[(QA) * 4 + mf][(QB) * 2 + nf] = __builtin_amdgcn_mfma_f32_16x16x32_bf16( \
          bq[nf * 2 + 1], aq[mf * 2 + 1], acc[(QA) * 4 + mf][(QB) * 2 + nf], 0, 0, 0); } \
    __builtin_amdgcn_s_setprio(0); } while (0)
#define PH_BAR() do { asm volatile("s_barrier" ::: "memory"); \
    __builtin_amdgcn_sched_barrier(0); } while (0)
#define VMC(n) do { asm volatile("s_waitcnt vmcnt(" #n ")" ::: "memory"); \
    __builtin_amdgcn_sched_barrier(0); } while (0)

  f32x4 acc[8][4];
#pragma unroll
  for (int i = 0; i < 8; i++)
#pragma unroll
    for (int j = 0; j < 4; j++) acc[i][j] = (f32x4){0.f, 0.f, 0.f, 0.f};

  bf16x8 afr[8], bfr0[4], bfr1[4];

  // prologue: tile0 complete -> buf0; tile1 {A0,B0} -> buf1.
  ST0(aSrc, 0, 0, 0); ST0(bSrc, 0, 0, 16384); ST0(bSrc, 1, 0, 24576); ST0(aSrc, 1, 0, 8192);
  ST0(aSrc, 0, 1, 32768); ST0(bSrc, 0, 1, 32768 + 16384);
  VMC(4); PH_BAR();

  // staging pointers (post-prologue), advance +64 elems per executed stage
  const unsigned short* pB1[2] = {bSrc[1][0] + 64, bSrc[1][1] + 64};
  const unsigned short* pA1[2] = {aSrc[1][0] + 64, aSrc[1][1] + 64};
  const unsigned short* pA0[2] = {aSrc[0][0] + 128, aSrc[0][1] + 128};
  const unsigned short* pB0[2] = {bSrc[0][0] + 128, bSrc[0][1] + 128};

#pragma unroll 2
  for (int t = 0; t < NTk; ++t) {
    int bo = (t & 1) << 15, bn = bo ^ 32768;
    bool g1 = (t + 1 < NTk), g2 = (t + 2 < NTk);
    // P1: read A0,B0(t); stage B1(t+1)->bn; vmcnt(8); bar; Q00
    RD_A(afr, 0, bo);
    RD_B(bfr0, 0, bo);
    ST_P(pB1, bn + 24576, g1);
    VMC(8); PH_BAR();
    MMQ(afr, bfr0, 0, 0);
    // P2: read B1(t); stage A1(t+1)->bn; bar; Q01
    RD_B(bfr1, 1, bo);
    ST_P(pA1, bn + 8192, g1);
    PH_BAR();
    MMQ(afr, bfr1, 0, 1);
    // P3: read A1(t); stage A0(t+2)->bo; vmcnt(8); bar; Q11
    RD_A(afr, 1, bo);
    ST_P(pA0, bo, g2);
    VMC(8); PH_BAR();
    MMQ(afr, bfr1, 1, 1);
    // P4: no reads; stage B0(t+2)->bo; bar; Q10 (regs only)
    ST_P(pB0, bo + 16384, g2);
    PH_BAR();
    MMQ(afr, bfr0, 1, 0);
  }
  asm volatile("s_waitcnt vmcnt(0)" ::: "memory");
  __builtin_amdgcn_sched_barrier(0);
#undef ST0
#undef ST_P
#undef RD_A
#undef RD_B
#undef MMQ
#undef PH_BAR
#undef VMC

#pragma unroll
  for (int mh = 0; mh < 2; mh++)
#pragma unroll
    for (int mf = 0; mf < 4; mf++) {
      size_t p = m0 + wm * 128 + mh * 64 + mf * 16 + lo;
      float w = (MODE == 0) ? 0.f : pair_w[p];
#pragma unroll
      for (int nf = 0; nf < 4; nf++) {
        int f = n0 + wn * 64 + nf * 16 + hi * 4;
        us4 pk;
#pragma unroll
        for (int r = 0; r < 4; r++) {
          float v = acc[mh * 4 + mf][nf][r];
          if (MODE == 0) {
            float u = fmaf(0.044715f * v * v, v, v);
            float s = 1.f / (1.f + __expf(-1.5957691216057308f * u));
            pk[r] = f2bf(v * s);
          } else {
            pk[r] = f2bf(w * v);
          }
        }
        *(us4*)&outbf[p * (size_t)OSTRIDE + f] = pk;
      }
    }
}

// ---------------- combine (+ fused finalize in global idx 0)
__global__ __launch_bounds__(256) void combine_kernel(
    const unsigned short* __restrict__ hout, const int* __restrict__ inv0,
    const int* __restrict__ inv1, float* __restrict__ outp,
    const float* __restrict__ scal) {
  int idx = blockIdx.x * 256 + threadIdx.x;
  int t = idx >> 7;                  // 128 threads per token row
  int c = (idx & 127) * 8;
  int p0 = inv0[t], p1 = inv1[t];
  bf16x8 va = *(const bf16x8*)&hout[(size_t)p0 * F_DIM + c];
  bf16x8 vb = *(const bf16x8*)&hout[(size_t)p1 * F_DIM + c];
  float* orow = outp + (size_t)t * H_DIM + c;
  float4 o0, o1;
  o0.x = bf2f((unsigned short)va[0]) + bf2f((unsigned short)vb[0]);
  o0.y = bf2f((unsigned short)va[1]) + bf2f((unsigned short)vb[1]);
  o0.z = bf2f((unsigned short)va[2]) + bf2f((unsigned short)vb[2]);
  o0.w = bf2f((unsigned short)va[3]) + bf2f((unsigned short)vb[3]);
  o1.x = bf2f((unsigned short)va[4]) + bf2f((unsigned short)vb[4]);
  o1.y = bf2f((unsigned short)va[5]) + bf2f((unsigned short)vb[5]);
  o1.z = bf2f((unsigned short)va[6]) + bf2f((unsigned short)vb[6]);
  o1.w = bf2f((unsigned short)va[7]) + bf2f((unsigned short)vb[7]);
  *(float4*)&orow[0] = o0;
  *(float4*)&orow[4] = o1;
  if (idx == 0) {
    float invT = 1.f / (float)T_TOKENS;
    float* outTail = outp + (size_t)T_TOKENS * H_DIM;
    outTail[0] = scal[0] * invT;  // z_loss
    float tpe0 = scal[1] * invT, tpe1 = scal[2] * invT;
    float rp0 = scal[3] * invT, rp1 = scal[4] * invT;
    outTail[1] = (tpe0 * rp0 + tpe1 * rp1) * 0.5f * 4.f;  // aux (K=2 one_hot path)
  }
}

extern "C" void kernel_launch(void* const* d_in, const int* in_sizes, int n_in,
                              void* d_out, int out_size, void* d_ws, size_t ws_size,
                              hipStream_t stream) {
  const float* x  = (const float*)d_in[0];
  const float* Wg = (const float*)d_in[1];
  const float* W1 = (const float*)d_in[2];
  const float* W2 = (const float*)d_in[3];
  float* outp = (float*)d_out;

  char* w = (char*)d_ws;
  auto alloc = [&](size_t b) { char* p = w; w += (b + 511) & ~(size_t)511; return p; };
  char*  meta        = alloc(256);
  float* scal        = (float*)(meta + 0);
  int*   counts      = (int*)(meta + 64);
  int*   cursors     = (int*)(meta + 128);
  int*   po          = (int*)alloc(64);
  int*   tile_expert = (int*)alloc(TOT_T * 4);
  TopK*  topk        = (TopK*)alloc((size_t)T_TOKENS * sizeof(TopK));
  int*   pair_token  = (int*)alloc((size_t)MAX_PAIRS * 4);
  float* pair_w      = (float*)alloc((size_t)MAX_PAIRS * 4);
  int*   inv0        = (int*)alloc((size_t)T_TOKENS * 4);
  int*   inv1        = (int*)alloc((size_t)T_TOKENS * 4);
  unsigned short* xb   = (unsigned short*)alloc((size_t)T_TOKENS * H_DIM * 2 + 512);
  unsigned short* w1t  = (unsigned short*)alloc((size_t)E_NUM * F_DIM * H_DIM * 2 + 512);
  unsigned short* hmid = (unsigned short*)alloc((size_t)MAX_PAIRS * F_DIM * 2 + 512);
  // w2t lives in d_out (64MB; w2t needs 32MB). d_out is scratch until combine,
  // which overwrites every element afterward. No workspace growth, no branches.
  unsigned short* w2t = (unsigned short*)d_out;

  hipFuncSetAttribute((const void*)&moe_gemm8<0, H_DIM, F_DIM, TOT_T>,
                      hipFuncAttributeMaxDynamicSharedMemorySize, 131072);
  hipFuncSetAttribute((const void*)&moe_gemm8<1, F_DIM, H_DIM, TOT_T>,
                      hipFuncAttributeMaxDynamicSharedMemorySize, 131072);

  hipMemsetAsync(meta, 0, 256, stream);
  hipMemsetAsync(pair_token, 0xFF, (size_t)MAX_PAIRS * 4, stream);  // -1

  dim3 b256(256), b512(512);
  // fused prep: router (1024) + W1 transpose (4096) + W2 transpose (4096)
  prep_kernel<<<dim3(9216), b256, 0, stream>>>(x, Wg, W1, W2, xb, w1t, w2t,
                                               topk, counts, scal);
  scan_kernel<<<1, b256, 0, stream>>>(counts, po, tile_expert);
  assign_kernel<<<T_TOKENS / 256, b256, 0, stream>>>(topk, po, cursors, pair_token, pair_w,
                                                     inv0, inv1);
  // GEMM1: hmid = gelu(gather(xb) @ W1t^T), both rank regions, one dispatch
  moe_gemm8<0, H_DIM, F_DIM, TOT_T><<<dim3((F_DIM / 256) * TOT_T), b512, 131072, stream>>>(
      xb, w1t, pair_token, pair_w, tile_expert, 0, hmid);
  // GEMM2: ONE dispatch, all 144 m-tiles; writes bf16 w(p)*(hmid[p]@W2t^T)
  // in-place into hmid[p][0:1024) (rows disjoint per block, reads precede writes)
  moe_gemm8<1, F_DIM, H_DIM, TOT_T><<<dim3((H_DIM / 256) * TOT_T), b512, 131072, stream>>>(
      hmid, w2t, pair_token, pair_w, tile_expert, 0, hmid);
  // combine + fused finalize (overwrites all of d_out, incl. the w2t scratch区)
  combine_kernel<<<dim3(T_TOKENS * 128 / 256), b256, 0, stream>>>(hmid, inv0, inv1, outp, scal);
}